// Round 2
// baseline (1068.675 us; speedup 1.0000x reference)
//
#include <hip/hip_runtime.h>

#define NN 25000
#define NE 400000
#define TT 4
#define NDIM 128
#define EDIM 64
#define NO 32
#define EO 64
#define DD 128
#define OUTD 128

// ws offsets (in floats)
#define OFF_Z      0
#define OFF_ASRC   800000
#define OFF_BSRC   825000
#define OFF_BDST   850000
#define OFF_C1     875000
#define OFF_C2     1275000
#define OFF_S1X    1675000
#define OFF_GAMMA  2075000
#define OFF_S2X    2475000
#define OFF_ALPHA  2875000
#define OFF_M1     3275000
#define OFF_DEN1   3300000
#define OFF_M2     3325000
#define OFF_DEN2   3350000
#define OFF_ZPHI   3375000
#define OFF_BETA   3375512
#define OFF_HBETA  3376000
#define WS_FLOATS  6576000

__device__ __forceinline__ unsigned f2o(float f) {
    unsigned u = __float_as_uint(f);
    return (u & 0x80000000u) ? ~u : (u | 0x80000000u);
}
__device__ __forceinline__ float o2f(unsigned o) {
    unsigned u = (o & 0x80000000u) ? (o & 0x7fffffffu) : ~o;
    return __uint_as_float(u);
}
__device__ __forceinline__ float lrelu(float x) { return x > 0.f ? x : 0.01f * x; }

// ---- K1: z = nf @ W_n ; per-node scalars a_src, b_src, b_dst ----
__global__ __launch_bounds__(256) void k_node(const float* __restrict__ nf,
    const float* __restrict__ W_n, const float* __restrict__ w_eattn,
    const float* __restrict__ w_attn, float* __restrict__ z,
    float* __restrict__ a_src, float* __restrict__ b_src, float* __restrict__ b_dst)
{
    __shared__ float Wl[128 * 32];
    __shared__ float nl[8 * 128];
    int tid = threadIdx.x;
    for (int i = tid; i < 128 * 32 / 4; i += 256)
        ((float4*)Wl)[i] = ((const float4*)W_n)[i];
    int nb = blockIdx.x * 8;
    ((float4*)nl)[tid] = ((const float4*)(nf + (size_t)nb * 128))[tid];
    __syncthreads();
    int node = tid >> 5;
    int col = tid & 31;
    float acc = 0.f;
    #pragma unroll 8
    for (int k = 0; k < 128; ++k)
        acc += nl[node * 128 + k] * Wl[k * 32 + col];
    int n = nb + node;
    z[(size_t)n * 32 + col] = acc;
    float va = acc * w_eattn[64 + col];
    float vb = acc * w_attn[col];
    float vc = acc * w_attn[96 + col];
    #pragma unroll
    for (int m = 16; m >= 1; m >>= 1) {
        va += __shfl_xor(va, m);
        vb += __shfl_xor(vb, m);
        vc += __shfl_xor(vc, m);
    }
    if (col == 0) { a_src[n] = va; b_src[n] = vb; b_dst[n] = vc; }
}

// ---- K2: e_ft = ef @ W_e (written to out e_w region); c1, c2 ----
__global__ __launch_bounds__(256) void k_edge(const float* __restrict__ ef,
    const float* __restrict__ W_e, const float* __restrict__ w_eattn,
    const float* __restrict__ w_attn, float* __restrict__ eft_out,
    float* __restrict__ c1, float* __restrict__ c2)
{
    __shared__ float Wl[64 * 64];
    __shared__ float el[16 * 65];
    int tid = threadIdx.x;
    for (int i = tid; i < 64 * 64 / 4; i += 256)
        ((float4*)Wl)[i] = ((const float4*)W_e)[i];
    size_t eb = (size_t)blockIdx.x * 16;
    {
        float4 v = ((const float4*)(ef + eb * 64))[tid];
        int r = (tid * 4) / 64, k0 = (tid * 4) % 64;
        el[r * 65 + k0] = v.x; el[r * 65 + k0 + 1] = v.y;
        el[r * 65 + k0 + 2] = v.z; el[r * 65 + k0 + 3] = v.w;
    }
    __syncthreads();
    int ein = tid >> 4;
    int c0 = (tid & 15) * 4;
    float a0 = 0, a1 = 0, a2 = 0, a3 = 0;
    #pragma unroll 4
    for (int k = 0; k < 64; ++k) {
        float a = el[ein * 65 + k];
        const float* wr = &Wl[k * 64 + c0];
        a0 += a * wr[0]; a1 += a * wr[1]; a2 += a * wr[2]; a3 += a * wr[3];
    }
    size_t e = eb + ein;
    float4 o; o.x = a0; o.y = a1; o.z = a2; o.w = a3;
    ((float4*)(eft_out + e * 64))[c0 >> 2] = o;
    float p1 = a0 * w_eattn[c0] + a1 * w_eattn[c0 + 1] + a2 * w_eattn[c0 + 2] + a3 * w_eattn[c0 + 3];
    float p2 = a0 * w_attn[32 + c0] + a1 * w_attn[33 + c0] + a2 * w_attn[34 + c0] + a3 * w_attn[35 + c0];
    #pragma unroll
    for (int m = 8; m >= 1; m >>= 1) {
        p1 += __shfl_xor(p1, m);
        p2 += __shfl_xor(p2, m);
    }
    if ((tid & 15) == 0) { c1[e] = p1; c2[e] = p2; }
}

// ---- K3: s1 + segment max over src ----
__global__ void k_s1(const float* __restrict__ c1, const float* __restrict__ a_src,
                     const int* __restrict__ src, float* __restrict__ s1x, unsigned* __restrict__ m1)
{
    int e = blockIdx.x * 256 + threadIdx.x;
    if (e >= NE) return;
    int s = src[e];
    float v = lrelu(c1[e] + a_src[s]);
    s1x[e] = v;
    atomicMax(&m1[s], f2o(v));
}

// ---- K4: ex1 = exp(s1-m1); den1 += ----
__global__ void k_ex1(const int* __restrict__ src, float* __restrict__ s1x,
                      const unsigned* __restrict__ m1, float* __restrict__ den1)
{
    int e = blockIdx.x * 256 + threadIdx.x;
    if (e >= NE) return;
    int s = src[e];
    float ex = expf(s1x[e] - o2f(m1[s]));
    s1x[e] = ex;
    atomicAdd(&den1[s], ex);
}

// ---- K5: gamma; s2; segment max over dst ----
__global__ void k_gamma_s2(const int* __restrict__ src, const int* __restrict__ dst,
    const float* __restrict__ s1x, const float* __restrict__ den1,
    const float* __restrict__ c2, const float* __restrict__ b_src, const float* __restrict__ b_dst,
    float* __restrict__ gamma, float* __restrict__ s2x, unsigned* __restrict__ m2)
{
    int e = blockIdx.x * 256 + threadIdx.x;
    if (e >= NE) return;
    int s = src[e], t = dst[e];
    float g = s1x[e] / den1[s];
    gamma[e] = g;
    float v = lrelu(b_src[s] + g * c2[e] + b_dst[t]);
    s2x[e] = v;
    atomicMax(&m2[t], f2o(v));
}

// ---- K5b: e_w *= gamma (in place on out region) ----
__global__ void k_scale_ew(float* __restrict__ ew, const float* __restrict__ gamma)
{
    size_t total = (size_t)NE * 16;  // float4 count
    size_t stride = (size_t)gridDim.x * 256;
    for (size_t i = (size_t)blockIdx.x * 256 + threadIdx.x; i < total; i += stride) {
        size_t e = i >> 4;
        float g = gamma[e];
        float4 v = ((float4*)ew)[i];
        v.x *= g; v.y *= g; v.z *= g; v.w *= g;
        ((float4*)ew)[i] = v;
    }
}

// ---- K6: ex2 = exp(s2-m2); den2 += ----
__global__ void k_ex2(const int* __restrict__ dst, float* __restrict__ s2x,
                      const unsigned* __restrict__ m2, float* __restrict__ den2)
{
    int e = blockIdx.x * 256 + threadIdx.x;
    if (e >= NE) return;
    int t = dst[e];
    float ex = expf(s2x[e] - o2f(m2[t]));
    s2x[e] = ex;
    atomicAdd(&den2[t], ex);
}

// ---- K7: alpha store + zphi per-type global reduction ----
// 32 lanes per edge; lane covers d0 = lane*4 .. +3 (float4).
__global__ __launch_bounds__(256) void k_zphi(const int* __restrict__ src, const int* __restrict__ dst,
    const int* __restrict__ ety, const float* __restrict__ s2x, const float* __restrict__ den2,
    const float* __restrict__ z, const float* __restrict__ ew,
    float* __restrict__ alpha, float* __restrict__ zphi)
{
    __shared__ float zl[512];
    int tid = threadIdx.x;
    zl[tid] = 0.f; zl[tid + 256] = 0.f;
    __syncthreads();
    int lane = tid & 31;
    int grp = tid >> 5;
    int d0 = lane * 4;
    float4 a0 = make_float4(0, 0, 0, 0), a1 = a0, a2 = a0, a3 = a0;
    int estep = gridDim.x * 8;
    for (int e = blockIdx.x * 8 + grp; e < NE; e += estep) {
        int dn = dst[e];
        float al = s2x[e] / den2[dn];
        if (lane == 0) alpha[e] = al;
        const float* p;
        if (lane < 8)       p = &z[(size_t)src[e] * 32 + d0];
        else if (lane < 24) p = &ew[(size_t)e * 64 + (d0 - 32)];
        else                p = &z[(size_t)dn * 32 + (d0 - 96)];
        float4 md = *(const float4*)p;
        int t = ety[e];
        float w0 = (t == 0) ? al : 0.f, w1 = (t == 1) ? al : 0.f;
        float w2 = (t == 2) ? al : 0.f, w3 = (t == 3) ? al : 0.f;
        a0.x += w0 * md.x; a0.y += w0 * md.y; a0.z += w0 * md.z; a0.w += w0 * md.w;
        a1.x += w1 * md.x; a1.y += w1 * md.y; a1.z += w1 * md.z; a1.w += w1 * md.w;
        a2.x += w2 * md.x; a2.y += w2 * md.y; a2.z += w2 * md.z; a2.w += w2 * md.w;
        a3.x += w3 * md.x; a3.y += w3 * md.y; a3.z += w3 * md.z; a3.w += w3 * md.w;
    }
    atomicAdd(&zl[0 * 128 + d0 + 0], a0.x); atomicAdd(&zl[0 * 128 + d0 + 1], a0.y);
    atomicAdd(&zl[0 * 128 + d0 + 2], a0.z); atomicAdd(&zl[0 * 128 + d0 + 3], a0.w);
    atomicAdd(&zl[1 * 128 + d0 + 0], a1.x); atomicAdd(&zl[1 * 128 + d0 + 1], a1.y);
    atomicAdd(&zl[1 * 128 + d0 + 2], a1.z); atomicAdd(&zl[1 * 128 + d0 + 3], a1.w);
    atomicAdd(&zl[2 * 128 + d0 + 0], a2.x); atomicAdd(&zl[2 * 128 + d0 + 1], a2.y);
    atomicAdd(&zl[2 * 128 + d0 + 2], a2.z); atomicAdd(&zl[2 * 128 + d0 + 3], a2.w);
    atomicAdd(&zl[3 * 128 + d0 + 0], a3.x); atomicAdd(&zl[3 * 128 + d0 + 1], a3.y);
    atomicAdd(&zl[3 * 128 + d0 + 2], a3.z); atomicAdd(&zl[3 * 128 + d0 + 3], a3.w);
    __syncthreads();
    atomicAdd(&zphi[tid], zl[tid]);
    atomicAdd(&zphi[tid + 256], zl[tid + 256]);
}

// ---- K8: beta = softmax(lrelu(zphi @ w_sem)) ----
__global__ __launch_bounds__(128) void k_beta(const float* __restrict__ zphi,
    const float* __restrict__ w_sem, float* __restrict__ beta)
{
    int tid = threadIdx.x;
    float w = w_sem[tid];
    float p0 = zphi[tid] * w, p1 = zphi[128 + tid] * w;
    float p2 = zphi[256 + tid] * w, p3 = zphi[384 + tid] * w;
    #pragma unroll
    for (int m = 32; m >= 1; m >>= 1) {
        p0 += __shfl_xor(p0, m); p1 += __shfl_xor(p1, m);
        p2 += __shfl_xor(p2, m); p3 += __shfl_xor(p3, m);
    }
    __shared__ float s[2][4];
    if ((tid & 63) == 0) {
        int w_ = tid >> 6;
        s[w_][0] = p0; s[w_][1] = p1; s[w_][2] = p2; s[w_][3] = p3;
    }
    __syncthreads();
    if (tid == 0) {
        float d0 = lrelu(s[0][0] + s[1][0]);
        float d1 = lrelu(s[0][1] + s[1][1]);
        float d2 = lrelu(s[0][2] + s[1][2]);
        float d3 = lrelu(s[0][3] + s[1][3]);
        float mx = fmaxf(fmaxf(d0, d1), fmaxf(d2, d3));
        float e0 = expf(d0 - mx), e1 = expf(d1 - mx), e2 = expf(d2 - mx), e3 = expf(d3 - mx);
        float inv = 1.f / (e0 + e1 + e2 + e3);
        beta[0] = e0 * inv; beta[1] = e1 * inv; beta[2] = e2 * inv; beta[3] = e3 * inv;
    }
}

// ---- K9: hbeta[dst] += alpha*beta[t]*msg (atomic scatter), 32 lanes/edge ----
__global__ __launch_bounds__(256) void k_scatter(const int* __restrict__ src, const int* __restrict__ dst,
    const int* __restrict__ ety, const float* __restrict__ alpha, const float* __restrict__ beta,
    const float* __restrict__ z, const float* __restrict__ ew, float* __restrict__ hbeta)
{
    int tid = threadIdx.x;
    int lane = tid & 31;
    int grp = tid >> 5;
    int d0 = lane * 4;
    int estep = gridDim.x * 8;
    for (int e = blockIdx.x * 8 + grp; e < NE; e += estep) {
        int dn = dst[e];
        float w = alpha[e] * beta[ety[e]];
        const float* p;
        if (lane < 8)       p = &z[(size_t)src[e] * 32 + d0];
        else if (lane < 24) p = &ew[(size_t)e * 64 + (d0 - 32)];
        else                p = &z[(size_t)dn * 32 + (d0 - 96)];
        float4 md = *(const float4*)p;
        float* hb = &hbeta[(size_t)dn * 128 + d0];
        atomicAdd(hb + 0, w * md.x);
        atomicAdd(hb + 1, w * md.y);
        atomicAdd(hb + 2, w * md.z);
        atomicAdd(hb + 3, w * md.w);
    }
}

// ---- K10: Z = hbeta @ W_fc2 ----
__global__ __launch_bounds__(256) void k_fc(const float* __restrict__ hb,
    const float* __restrict__ W, float* __restrict__ Z)
{
    __shared__ float hl[32 * 132];
    __shared__ float Wl[128 * 64];
    int tid = threadIdx.x;
    int nb = blockIdx.x * 32;
    for (int i = tid; i < 1024; i += 256) {
        int row = i >> 5, kc = (i & 31) * 4;
        float4 v = make_float4(0.f, 0.f, 0.f, 0.f);
        if (nb + row < NN) v = *(const float4*)&hb[(size_t)(nb + row) * 128 + kc];
        *(float4*)&hl[row * 132 + kc] = v;
    }
    for (int half = 0; half < 2; ++half) {
        __syncthreads();
        for (int i = tid; i < 2048; i += 256) {
            int k = i >> 4, c = (i & 15) * 4;
            *(float4*)&Wl[k * 64 + c] = *(const float4*)&W[(size_t)k * 128 + half * 64 + c];
        }
        __syncthreads();
        int node = tid >> 3;
        int c0 = (tid & 7) * 8;
        float acc[8] = {0, 0, 0, 0, 0, 0, 0, 0};
        #pragma unroll 4
        for (int k = 0; k < 128; ++k) {
            float a = hl[node * 132 + k];
            const float* wr = &Wl[k * 64 + c0];
            #pragma unroll
            for (int j = 0; j < 8; ++j) acc[j] += a * wr[j];
        }
        int n = nb + node;
        if (n < NN) {
            float4 o1, o2;
            o1.x = acc[0]; o1.y = acc[1]; o1.z = acc[2]; o1.w = acc[3];
            o2.x = acc[4]; o2.y = acc[5]; o2.z = acc[6]; o2.w = acc[7];
            *(float4*)&Z[(size_t)n * 128 + half * 64 + c0] = o1;
            *(float4*)&Z[(size_t)n * 128 + half * 64 + c0 + 4] = o2;
        }
    }
}

extern "C" void kernel_launch(void* const* d_in, const int* in_sizes, int n_in,
                              void* d_out, int out_size, void* d_ws, size_t ws_size,
                              hipStream_t stream)
{
    const float* nf     = (const float*)d_in[0];
    const float* ef     = (const float*)d_in[1];
    const int*   src    = (const int*)d_in[2];
    const int*   dst    = (const int*)d_in[3];
    const int*   ety    = (const int*)d_in[4];
    const float* W_n    = (const float*)d_in[5];
    const float* W_e    = (const float*)d_in[6];
    const float* w_eattn= (const float*)d_in[7];
    const float* w_attn = (const float*)d_in[8];
    const float* w_sem  = (const float*)d_in[9];
    const float* W_fc2  = (const float*)d_in[10];

    float* out = (float*)d_out;
    float* Z   = out;
    float* ew  = out + (size_t)NN * OUTD;

    float* ws    = (float*)d_ws;
    float* z     = ws + OFF_Z;
    float* a_src = ws + OFF_ASRC;
    float* b_src = ws + OFF_BSRC;
    float* b_dst = ws + OFF_BDST;
    float* c1    = ws + OFF_C1;
    float* c2    = ws + OFF_C2;
    float* s1x   = ws + OFF_S1X;
    float* gamma = ws + OFF_GAMMA;
    float* s2x   = ws + OFF_S2X;
    float* alpha = ws + OFF_ALPHA;
    unsigned* m1 = (unsigned*)(ws + OFF_M1);
    float* den1  = ws + OFF_DEN1;
    unsigned* m2 = (unsigned*)(ws + OFF_M2);
    float* den2  = ws + OFF_DEN2;
    float* zphi  = ws + OFF_ZPHI;
    float* beta  = ws + OFF_BETA;
    float* hbeta = ws + OFF_HBETA;

    // zero: m1, den1, m2, den2, zphi, beta, hbeta (contiguous)
    hipMemsetAsync(ws + OFF_M1, 0, (size_t)(WS_FLOATS - OFF_M1) * 4, stream);

    k_node<<<NN / 8, 256, 0, stream>>>(nf, W_n, w_eattn, w_attn, z, a_src, b_src, b_dst);
    k_edge<<<NE / 16, 256, 0, stream>>>(ef, W_e, w_eattn, w_attn, ew, c1, c2);
    int gE = (NE + 255) / 256;
    k_s1<<<gE, 256, 0, stream>>>(c1, a_src, src, s1x, m1);
    k_ex1<<<gE, 256, 0, stream>>>(src, s1x, m1, den1);
    k_gamma_s2<<<gE, 256, 0, stream>>>(src, dst, s1x, den1, c2, b_src, b_dst, gamma, s2x, m2);
    k_scale_ew<<<4096, 256, 0, stream>>>(ew, gamma);
    k_ex2<<<gE, 256, 0, stream>>>(dst, s2x, m2, den2);
    k_zphi<<<1024, 256, 0, stream>>>(src, dst, ety, s2x, den2, z, ew, alpha, zphi);
    k_beta<<<1, 128, 0, stream>>>(zphi, w_sem, beta);
    k_scatter<<<2048, 256, 0, stream>>>(src, dst, ety, alpha, beta, z, ew, hbeta);
    k_fc<<<(NN + 31) / 32, 256, 0, stream>>>(hbeta, W_fc2, Z);
}

// Round 3
// 532.487 us; speedup vs baseline: 2.0069x; 2.0069x over previous
//
#include <hip/hip_runtime.h>

#define NN 25000
#define NE 400000
#define TT 4
#define NDIM 128
#define EDIM 64
#define NO 32
#define EO 64
#define DD 128
#define OUTD 128

// ws offsets (in floats)
#define OFF_Z      0
#define OFF_ASRC   800000
#define OFF_BSRC   825000
#define OFF_BDST   850000
#define OFF_C1     875000
#define OFF_C2     1275000
#define OFF_S1X    1675000
#define OFF_GAMMA  2075000
#define OFF_S2X    2475000
#define OFF_ALPHA  2875000
// ---- memset zone [OFF_M1, OFF_OFFS) ----
#define OFF_M1     3275000
#define OFF_DEN1   3300000
#define OFF_M2     3325000
#define OFF_DEN2   3350000
#define OFF_ZPHI   3375000
#define OFF_BETA   3375512
#define OFF_DEG    3376000
// ---- end memset zone ----
#define OFF_OFFS   3401000
#define OFF_CURSOR 3426004
#define OFF_EIDX   3451004
#define OFF_HBETA  3851008
#define WS_FLOATS  7051008

__device__ __forceinline__ unsigned f2o(float f) {
    unsigned u = __float_as_uint(f);
    return (u & 0x80000000u) ? ~u : (u | 0x80000000u);
}
__device__ __forceinline__ float o2f(unsigned o) {
    unsigned u = (o & 0x80000000u) ? (o & 0x7fffffffu) : ~o;
    return __uint_as_float(u);
}
__device__ __forceinline__ float lrelu(float x) { return x > 0.f ? x : 0.01f * x; }

// ---- K1: z = nf @ W_n ; per-node scalars a_src, b_src, b_dst ----
__global__ __launch_bounds__(256) void k_node(const float* __restrict__ nf,
    const float* __restrict__ W_n, const float* __restrict__ w_eattn,
    const float* __restrict__ w_attn, float* __restrict__ z,
    float* __restrict__ a_src, float* __restrict__ b_src, float* __restrict__ b_dst)
{
    __shared__ float Wl[128 * 32];
    __shared__ float nl[8 * 128];
    int tid = threadIdx.x;
    for (int i = tid; i < 128 * 32 / 4; i += 256)
        ((float4*)Wl)[i] = ((const float4*)W_n)[i];
    int nb = blockIdx.x * 8;
    ((float4*)nl)[tid] = ((const float4*)(nf + (size_t)nb * 128))[tid];
    __syncthreads();
    int node = tid >> 5;
    int col = tid & 31;
    float acc = 0.f;
    #pragma unroll 8
    for (int k = 0; k < 128; ++k)
        acc += nl[node * 128 + k] * Wl[k * 32 + col];
    int n = nb + node;
    z[(size_t)n * 32 + col] = acc;
    float va = acc * w_eattn[64 + col];
    float vb = acc * w_attn[col];
    float vc = acc * w_attn[96 + col];
    #pragma unroll
    for (int m = 16; m >= 1; m >>= 1) {
        va += __shfl_xor(va, m);
        vb += __shfl_xor(vb, m);
        vc += __shfl_xor(vc, m);
    }
    if (col == 0) { a_src[n] = va; b_src[n] = vb; b_dst[n] = vc; }
}

// ---- K2: e_ft = ef @ W_e (RAW, written to out e_w region); c1, c2 ----
__global__ __launch_bounds__(256) void k_edge(const float* __restrict__ ef,
    const float* __restrict__ W_e, const float* __restrict__ w_eattn,
    const float* __restrict__ w_attn, float* __restrict__ eft_out,
    float* __restrict__ c1, float* __restrict__ c2)
{
    __shared__ float Wl[64 * 64];
    __shared__ float el[16 * 65];
    int tid = threadIdx.x;
    for (int i = tid; i < 64 * 64 / 4; i += 256)
        ((float4*)Wl)[i] = ((const float4*)W_e)[i];
    size_t eb = (size_t)blockIdx.x * 16;
    {
        float4 v = ((const float4*)(ef + eb * 64))[tid];
        int r = (tid * 4) / 64, k0 = (tid * 4) % 64;
        el[r * 65 + k0] = v.x; el[r * 65 + k0 + 1] = v.y;
        el[r * 65 + k0 + 2] = v.z; el[r * 65 + k0 + 3] = v.w;
    }
    __syncthreads();
    int ein = tid >> 4;
    int c0 = (tid & 15) * 4;
    float a0 = 0, a1 = 0, a2 = 0, a3 = 0;
    #pragma unroll 4
    for (int k = 0; k < 64; ++k) {
        float a = el[ein * 65 + k];
        const float* wr = &Wl[k * 64 + c0];
        a0 += a * wr[0]; a1 += a * wr[1]; a2 += a * wr[2]; a3 += a * wr[3];
    }
    size_t e = eb + ein;
    float4 o; o.x = a0; o.y = a1; o.z = a2; o.w = a3;
    ((float4*)(eft_out + e * 64))[c0 >> 2] = o;
    float p1 = a0 * w_eattn[c0] + a1 * w_eattn[c0 + 1] + a2 * w_eattn[c0 + 2] + a3 * w_eattn[c0 + 3];
    float p2 = a0 * w_attn[32 + c0] + a1 * w_attn[33 + c0] + a2 * w_attn[34 + c0] + a3 * w_attn[35 + c0];
    #pragma unroll
    for (int m = 8; m >= 1; m >>= 1) {
        p1 += __shfl_xor(p1, m);
        p2 += __shfl_xor(p2, m);
    }
    if ((tid & 15) == 0) { c1[e] = p1; c2[e] = p2; }
}

// ---- K3: s1 + segment max over src + dst-degree histogram ----
__global__ void k_s1(const float* __restrict__ c1, const float* __restrict__ a_src,
                     const int* __restrict__ src, const int* __restrict__ dst,
                     float* __restrict__ s1x, unsigned* __restrict__ m1, int* __restrict__ deg)
{
    int e = blockIdx.x * 256 + threadIdx.x;
    if (e >= NE) return;
    int s = src[e];
    float v = lrelu(c1[e] + a_src[s]);
    s1x[e] = v;
    atomicMax(&m1[s], f2o(v));
    atomicAdd(&deg[dst[e]], 1);
}

// ---- K4: ex1 = exp(s1-m1); den1 += ----
__global__ void k_ex1(const int* __restrict__ src, float* __restrict__ s1x,
                      const unsigned* __restrict__ m1, float* __restrict__ den1)
{
    int e = blockIdx.x * 256 + threadIdx.x;
    if (e >= NE) return;
    int s = src[e];
    float ex = expf(s1x[e] - o2f(m1[s]));
    s1x[e] = ex;
    atomicAdd(&den1[s], ex);
}

// ---- K4b: exclusive prefix scan of deg -> offs, cursor (single block) ----
__global__ __launch_bounds__(1024) void k_scan(const int* __restrict__ deg,
    int* __restrict__ offs, int* __restrict__ cursor)
{
    __shared__ int buf[1024];
    __shared__ int carry_s;
    int tid = threadIdx.x;
    if (tid == 0) carry_s = 0;
    __syncthreads();
    for (int base = 0; base < NN; base += 1024) {
        int idx = base + tid;
        int v = (idx < NN) ? deg[idx] : 0;
        buf[tid] = v;
        __syncthreads();
        #pragma unroll
        for (int off = 1; off < 1024; off <<= 1) {
            int t = (tid >= off) ? buf[tid - off] : 0;
            __syncthreads();
            buf[tid] += t;
            __syncthreads();
        }
        int incl = buf[tid];
        int carry = carry_s;
        if (idx < NN) {
            int excl = carry + incl - v;
            offs[idx] = excl;
            cursor[idx] = excl;
        }
        __syncthreads();
        if (tid == 1023) carry_s = carry + buf[1023];
        __syncthreads();
    }
    if (tid == 0) offs[NN] = carry_s;
}

// ---- K5: gamma; s2; segment max over dst; CSR bucket fill ----
__global__ void k_gamma_s2(const int* __restrict__ src, const int* __restrict__ dst,
    const float* __restrict__ s1x, const float* __restrict__ den1,
    const float* __restrict__ c2, const float* __restrict__ b_src, const float* __restrict__ b_dst,
    float* __restrict__ gamma, float* __restrict__ s2x, unsigned* __restrict__ m2,
    int* __restrict__ cursor, int* __restrict__ eidx)
{
    int e = blockIdx.x * 256 + threadIdx.x;
    if (e >= NE) return;
    int s = src[e], t = dst[e];
    float g = s1x[e] / den1[s];
    gamma[e] = g;
    float v = lrelu(b_src[s] + g * c2[e] + b_dst[t]);
    s2x[e] = v;
    atomicMax(&m2[t], f2o(v));
    int pos = atomicAdd(&cursor[t], 1);
    eidx[pos] = e;
}

// ---- K6: ex2 = exp(s2-m2); den2 += ----
__global__ void k_ex2(const int* __restrict__ dst, float* __restrict__ s2x,
                      const unsigned* __restrict__ m2, float* __restrict__ den2)
{
    int e = blockIdx.x * 256 + threadIdx.x;
    if (e >= NE) return;
    int t = dst[e];
    float ex = expf(s2x[e] - o2f(m2[t]));
    s2x[e] = ex;
    atomicAdd(&den2[t], ex);
}

// ---- K7: alpha store + e_w scale (in place) + zphi per-type reduction ----
// 32 lanes per edge; lane covers d0 = lane*4 .. +3 (float4).
__global__ __launch_bounds__(256) void k_zphi(const int* __restrict__ src, const int* __restrict__ dst,
    const int* __restrict__ ety, const float* __restrict__ s2x, const float* __restrict__ den2,
    const float* __restrict__ gamma, const float* __restrict__ z, float* __restrict__ ew,
    float* __restrict__ alpha, float* __restrict__ zphi)
{
    __shared__ float zl[512];
    int tid = threadIdx.x;
    zl[tid] = 0.f; zl[tid + 256] = 0.f;
    __syncthreads();
    int lane = tid & 31;
    int grp = tid >> 5;
    int d0 = lane * 4;
    float4 a0 = make_float4(0, 0, 0, 0), a1 = a0, a2 = a0, a3 = a0;
    int estep = gridDim.x * 8;
    for (int e = blockIdx.x * 8 + grp; e < NE; e += estep) {
        int dn = dst[e];
        float al = s2x[e] / den2[dn];
        if (lane == 0) alpha[e] = al;
        float4 md;
        if (lane < 8) {
            md = *(const float4*)&z[(size_t)src[e] * 32 + d0];
        } else if (lane < 24) {
            float g = gamma[e];
            float4 raw = *(const float4*)&ew[(size_t)e * 64 + (d0 - 32)];
            md.x = g * raw.x; md.y = g * raw.y; md.z = g * raw.z; md.w = g * raw.w;
            *(float4*)&ew[(size_t)e * 64 + (d0 - 32)] = md;   // e_w output
        } else {
            md = *(const float4*)&z[(size_t)dn * 32 + (d0 - 96)];
        }
        int t = ety[e];
        float w0 = (t == 0) ? al : 0.f, w1 = (t == 1) ? al : 0.f;
        float w2 = (t == 2) ? al : 0.f, w3 = (t == 3) ? al : 0.f;
        a0.x += w0 * md.x; a0.y += w0 * md.y; a0.z += w0 * md.z; a0.w += w0 * md.w;
        a1.x += w1 * md.x; a1.y += w1 * md.y; a1.z += w1 * md.z; a1.w += w1 * md.w;
        a2.x += w2 * md.x; a2.y += w2 * md.y; a2.z += w2 * md.z; a2.w += w2 * md.w;
        a3.x += w3 * md.x; a3.y += w3 * md.y; a3.z += w3 * md.z; a3.w += w3 * md.w;
    }
    atomicAdd(&zl[0 * 128 + d0 + 0], a0.x); atomicAdd(&zl[0 * 128 + d0 + 1], a0.y);
    atomicAdd(&zl[0 * 128 + d0 + 2], a0.z); atomicAdd(&zl[0 * 128 + d0 + 3], a0.w);
    atomicAdd(&zl[1 * 128 + d0 + 0], a1.x); atomicAdd(&zl[1 * 128 + d0 + 1], a1.y);
    atomicAdd(&zl[1 * 128 + d0 + 2], a1.z); atomicAdd(&zl[1 * 128 + d0 + 3], a1.w);
    atomicAdd(&zl[2 * 128 + d0 + 0], a2.x); atomicAdd(&zl[2 * 128 + d0 + 1], a2.y);
    atomicAdd(&zl[2 * 128 + d0 + 2], a2.z); atomicAdd(&zl[2 * 128 + d0 + 3], a2.w);
    atomicAdd(&zl[3 * 128 + d0 + 0], a3.x); atomicAdd(&zl[3 * 128 + d0 + 1], a3.y);
    atomicAdd(&zl[3 * 128 + d0 + 2], a3.z); atomicAdd(&zl[3 * 128 + d0 + 3], a3.w);
    __syncthreads();
    atomicAdd(&zphi[tid], zl[tid]);
    atomicAdd(&zphi[tid + 256], zl[tid + 256]);
}

// ---- K8: beta = softmax(lrelu(zphi @ w_sem)) ----
__global__ __launch_bounds__(128) void k_beta(const float* __restrict__ zphi,
    const float* __restrict__ w_sem, float* __restrict__ beta)
{
    int tid = threadIdx.x;
    float w = w_sem[tid];
    float p0 = zphi[tid] * w, p1 = zphi[128 + tid] * w;
    float p2 = zphi[256 + tid] * w, p3 = zphi[384 + tid] * w;
    #pragma unroll
    for (int m = 32; m >= 1; m >>= 1) {
        p0 += __shfl_xor(p0, m); p1 += __shfl_xor(p1, m);
        p2 += __shfl_xor(p2, m); p3 += __shfl_xor(p3, m);
    }
    __shared__ float s[2][4];
    if ((tid & 63) == 0) {
        int w_ = tid >> 6;
        s[w_][0] = p0; s[w_][1] = p1; s[w_][2] = p2; s[w_][3] = p3;
    }
    __syncthreads();
    if (tid == 0) {
        float d0 = lrelu(s[0][0] + s[1][0]);
        float d1 = lrelu(s[0][1] + s[1][1]);
        float d2 = lrelu(s[0][2] + s[1][2]);
        float d3 = lrelu(s[0][3] + s[1][3]);
        float mx = fmaxf(fmaxf(d0, d1), fmaxf(d2, d3));
        float e0 = expf(d0 - mx), e1 = expf(d1 - mx), e2 = expf(d2 - mx), e3 = expf(d3 - mx);
        float inv = 1.f / (e0 + e1 + e2 + e3);
        beta[0] = e0 * inv; beta[1] = e1 * inv; beta[2] = e2 * inv; beta[3] = e3 * inv;
    }
}

// ---- K9: CSR scatter — one 32-lane group per node, no atomics ----
__global__ __launch_bounds__(256) void k_scatter(const int* __restrict__ offs,
    const int* __restrict__ eidx, const int* __restrict__ src, const int* __restrict__ ety,
    const float* __restrict__ alpha, const float* __restrict__ beta,
    const float* __restrict__ z, const float* __restrict__ ew, float* __restrict__ hbeta)
{
    int tid = threadIdx.x;
    int lane = tid & 31;
    int grp = tid >> 5;
    int n = blockIdx.x * 8 + grp;
    if (n >= NN) return;
    int d0 = lane * 4;
    int beg = offs[n], end = offs[n + 1];
    float b0 = beta[0], b1 = beta[1], b2 = beta[2], b3 = beta[3];
    float4 acc = make_float4(0, 0, 0, 0);
    float sumw = 0.f;
    for (int i = beg; i < end; ++i) {
        int e = eidx[i];
        int t = ety[e];
        float w = alpha[e] * (t == 0 ? b0 : t == 1 ? b1 : t == 2 ? b2 : b3);
        sumw += w;
        if (lane < 24) {
            const float* p = (lane < 8) ? &z[(size_t)src[e] * 32 + d0]
                                        : &ew[(size_t)e * 64 + (d0 - 32)];
            float4 md = *(const float4*)p;
            acc.x += w * md.x; acc.y += w * md.y; acc.z += w * md.z; acc.w += w * md.w;
        }
    }
    if (lane >= 24) {
        float4 zd = *(const float4*)&z[(size_t)n * 32 + (d0 - 96)];
        acc.x = sumw * zd.x; acc.y = sumw * zd.y; acc.z = sumw * zd.z; acc.w = sumw * zd.w;
    }
    *(float4*)&hbeta[(size_t)n * 128 + d0] = acc;
}

// ---- K10: Z = hbeta @ W_fc2 ----
__global__ __launch_bounds__(256) void k_fc(const float* __restrict__ hb,
    const float* __restrict__ W, float* __restrict__ Z)
{
    __shared__ float hl[32 * 132];
    __shared__ float Wl[128 * 64];
    int tid = threadIdx.x;
    int nb = blockIdx.x * 32;
    for (int i = tid; i < 1024; i += 256) {
        int row = i >> 5, kc = (i & 31) * 4;
        float4 v = make_float4(0.f, 0.f, 0.f, 0.f);
        if (nb + row < NN) v = *(const float4*)&hb[(size_t)(nb + row) * 128 + kc];
        *(float4*)&hl[row * 132 + kc] = v;
    }
    for (int half = 0; half < 2; ++half) {
        __syncthreads();
        for (int i = tid; i < 2048; i += 256) {
            int k = i >> 4, c = (i & 15) * 4;
            *(float4*)&Wl[k * 64 + c] = *(const float4*)&W[(size_t)k * 128 + half * 64 + c];
        }
        __syncthreads();
        int node = tid >> 3;
        int c0 = (tid & 7) * 8;
        float acc[8] = {0, 0, 0, 0, 0, 0, 0, 0};
        #pragma unroll 4
        for (int k = 0; k < 128; ++k) {
            float a = hl[node * 132 + k];
            const float* wr = &Wl[k * 64 + c0];
            #pragma unroll
            for (int j = 0; j < 8; ++j) acc[j] += a * wr[j];
        }
        int n = nb + node;
        if (n < NN) {
            float4 o1, o2;
            o1.x = acc[0]; o1.y = acc[1]; o1.z = acc[2]; o1.w = acc[3];
            o2.x = acc[4]; o2.y = acc[5]; o2.z = acc[6]; o2.w = acc[7];
            *(float4*)&Z[(size_t)n * 128 + half * 64 + c0] = o1;
            *(float4*)&Z[(size_t)n * 128 + half * 64 + c0 + 4] = o2;
        }
    }
}

extern "C" void kernel_launch(void* const* d_in, const int* in_sizes, int n_in,
                              void* d_out, int out_size, void* d_ws, size_t ws_size,
                              hipStream_t stream)
{
    const float* nf     = (const float*)d_in[0];
    const float* ef     = (const float*)d_in[1];
    const int*   src    = (const int*)d_in[2];
    const int*   dst    = (const int*)d_in[3];
    const int*   ety    = (const int*)d_in[4];
    const float* W_n    = (const float*)d_in[5];
    const float* W_e    = (const float*)d_in[6];
    const float* w_eattn= (const float*)d_in[7];
    const float* w_attn = (const float*)d_in[8];
    const float* w_sem  = (const float*)d_in[9];
    const float* W_fc2  = (const float*)d_in[10];

    float* out = (float*)d_out;
    float* Z   = out;
    float* ew  = out + (size_t)NN * OUTD;

    float* ws    = (float*)d_ws;
    float* z     = ws + OFF_Z;
    float* a_src = ws + OFF_ASRC;
    float* b_src = ws + OFF_BSRC;
    float* b_dst = ws + OFF_BDST;
    float* c1    = ws + OFF_C1;
    float* c2    = ws + OFF_C2;
    float* s1x   = ws + OFF_S1X;
    float* gamma = ws + OFF_GAMMA;
    float* s2x   = ws + OFF_S2X;
    float* alpha = ws + OFF_ALPHA;
    unsigned* m1 = (unsigned*)(ws + OFF_M1);
    float* den1  = ws + OFF_DEN1;
    unsigned* m2 = (unsigned*)(ws + OFF_M2);
    float* den2  = ws + OFF_DEN2;
    float* zphi  = ws + OFF_ZPHI;
    float* beta  = ws + OFF_BETA;
    int* deg     = (int*)(ws + OFF_DEG);
    int* offs    = (int*)(ws + OFF_OFFS);
    int* cursor  = (int*)(ws + OFF_CURSOR);
    int* eidx    = (int*)(ws + OFF_EIDX);
    float* hbeta = ws + OFF_HBETA;

    // zero: m1, den1, m2, den2, zphi, beta, deg (contiguous, ~500 KB)
    hipMemsetAsync(ws + OFF_M1, 0, (size_t)(OFF_OFFS - OFF_M1) * 4, stream);

    k_node<<<NN / 8, 256, 0, stream>>>(nf, W_n, w_eattn, w_attn, z, a_src, b_src, b_dst);
    k_edge<<<NE / 16, 256, 0, stream>>>(ef, W_e, w_eattn, w_attn, ew, c1, c2);
    int gE = (NE + 255) / 256;
    k_s1<<<gE, 256, 0, stream>>>(c1, a_src, src, dst, s1x, m1, deg);
    k_ex1<<<gE, 256, 0, stream>>>(src, s1x, m1, den1);
    k_scan<<<1, 1024, 0, stream>>>(deg, offs, cursor);
    k_gamma_s2<<<gE, 256, 0, stream>>>(src, dst, s1x, den1, c2, b_src, b_dst, gamma, s2x, m2, cursor, eidx);
    k_ex2<<<gE, 256, 0, stream>>>(dst, s2x, m2, den2);
    k_zphi<<<1024, 256, 0, stream>>>(src, dst, ety, s2x, den2, gamma, z, ew, alpha, zphi);
    k_beta<<<1, 128, 0, stream>>>(zphi, w_sem, beta);
    k_scatter<<<(NN + 7) / 8, 256, 0, stream>>>(offs, eidx, src, ety, alpha, beta, z, ew, hbeta);
    k_fc<<<(NN + 31) / 32, 256, 0, stream>>>(hbeta, W_fc2, Z);
}

// Round 4
// 473.218 us; speedup vs baseline: 2.2583x; 1.1252x over previous
//
#include <hip/hip_runtime.h>

#define NN 25000
#define NE 400000
#define TT 4
#define NDIM 128
#define EDIM 64
#define NO 32
#define EO 64
#define DD 128
#define OUTD 128

// ws offsets (in floats)
#define OFF_Z      0
#define OFF_ASRC   800000
#define OFF_BSRC   825000
#define OFF_BDST   850000
#define OFF_C1     875000
#define OFF_C2     1275000
#define OFF_S1X    1675000
#define OFF_GAMMA  2075000
#define OFF_S2X    2475000
#define OFF_ALPHA  2875000
// ---- memset zone [OFF_M1, OFF_OFFS) ----
#define OFF_M1     3275000
#define OFF_DEN1   3300000
#define OFF_M2     3325000
#define OFF_DEN2   3350000
#define OFF_ZPHI   3375000
#define OFF_BETA   3375512
#define OFF_DEG    3376000
// ---- end memset zone ----
#define OFF_OFFS   3401000
#define OFF_CURSOR 3426004
#define OFF_EIDX   3451004
#define OFF_HBETA  3851008
#define WS_FLOATS  7051008

__device__ __forceinline__ unsigned f2o(float f) {
    unsigned u = __float_as_uint(f);
    return (u & 0x80000000u) ? ~u : (u | 0x80000000u);
}
__device__ __forceinline__ float o2f(unsigned o) {
    unsigned u = (o & 0x80000000u) ? (o & 0x7fffffffu) : ~o;
    return __uint_as_float(u);
}
__device__ __forceinline__ float lrelu(float x) { return x > 0.f ? x : 0.01f * x; }

// ---- K1: z = nf @ W_n ; per-node scalars a_src, b_src, b_dst ----
__global__ __launch_bounds__(256) void k_node(const float* __restrict__ nf,
    const float* __restrict__ W_n, const float* __restrict__ w_eattn,
    const float* __restrict__ w_attn, float* __restrict__ z,
    float* __restrict__ a_src, float* __restrict__ b_src, float* __restrict__ b_dst)
{
    __shared__ float Wl[128 * 32];
    __shared__ float nl[8 * 128];
    int tid = threadIdx.x;
    for (int i = tid; i < 128 * 32 / 4; i += 256)
        ((float4*)Wl)[i] = ((const float4*)W_n)[i];
    int nb = blockIdx.x * 8;
    ((float4*)nl)[tid] = ((const float4*)(nf + (size_t)nb * 128))[tid];
    __syncthreads();
    int node = tid >> 5;
    int col = tid & 31;
    float acc = 0.f;
    #pragma unroll 8
    for (int k = 0; k < 128; ++k)
        acc += nl[node * 128 + k] * Wl[k * 32 + col];
    int n = nb + node;
    z[(size_t)n * 32 + col] = acc;
    float va = acc * w_eattn[64 + col];
    float vb = acc * w_attn[col];
    float vc = acc * w_attn[96 + col];
    #pragma unroll
    for (int m = 16; m >= 1; m >>= 1) {
        va += __shfl_xor(va, m);
        vb += __shfl_xor(vb, m);
        vc += __shfl_xor(vc, m);
    }
    if (col == 0) { a_src[n] = va; b_src[n] = vb; b_dst[n] = vc; }
}

// ---- K2: e_ft = ef @ W_e (RAW, written to out e_w region); c1, c2 ----
__global__ __launch_bounds__(256) void k_edge(const float* __restrict__ ef,
    const float* __restrict__ W_e, const float* __restrict__ w_eattn,
    const float* __restrict__ w_attn, float* __restrict__ eft_out,
    float* __restrict__ c1, float* __restrict__ c2)
{
    __shared__ float Wl[64 * 64];
    __shared__ float el[16 * 65];
    int tid = threadIdx.x;
    for (int i = tid; i < 64 * 64 / 4; i += 256)
        ((float4*)Wl)[i] = ((const float4*)W_e)[i];
    size_t eb = (size_t)blockIdx.x * 16;
    {
        float4 v = ((const float4*)(ef + eb * 64))[tid];
        int r = (tid * 4) / 64, k0 = (tid * 4) % 64;
        el[r * 65 + k0] = v.x; el[r * 65 + k0 + 1] = v.y;
        el[r * 65 + k0 + 2] = v.z; el[r * 65 + k0 + 3] = v.w;
    }
    __syncthreads();
    int ein = tid >> 4;
    int c0 = (tid & 15) * 4;
    float a0 = 0, a1 = 0, a2 = 0, a3 = 0;
    #pragma unroll 4
    for (int k = 0; k < 64; ++k) {
        float a = el[ein * 65 + k];
        const float* wr = &Wl[k * 64 + c0];
        a0 += a * wr[0]; a1 += a * wr[1]; a2 += a * wr[2]; a3 += a * wr[3];
    }
    size_t e = eb + ein;
    float4 o; o.x = a0; o.y = a1; o.z = a2; o.w = a3;
    ((float4*)(eft_out + e * 64))[c0 >> 2] = o;
    float p1 = a0 * w_eattn[c0] + a1 * w_eattn[c0 + 1] + a2 * w_eattn[c0 + 2] + a3 * w_eattn[c0 + 3];
    float p2 = a0 * w_attn[32 + c0] + a1 * w_attn[33 + c0] + a2 * w_attn[34 + c0] + a3 * w_attn[35 + c0];
    #pragma unroll
    for (int m = 8; m >= 1; m >>= 1) {
        p1 += __shfl_xor(p1, m);
        p2 += __shfl_xor(p2, m);
    }
    if ((tid & 15) == 0) { c1[e] = p1; c2[e] = p2; }
}

// ---- K3: s1 + segment max over src + dst-degree histogram ----
__global__ void k_s1(const float* __restrict__ c1, const float* __restrict__ a_src,
                     const int* __restrict__ src, const int* __restrict__ dst,
                     float* __restrict__ s1x, unsigned* __restrict__ m1, int* __restrict__ deg)
{
    int e = blockIdx.x * 256 + threadIdx.x;
    if (e >= NE) return;
    int s = src[e];
    float v = lrelu(c1[e] + a_src[s]);
    s1x[e] = v;
    atomicMax(&m1[s], f2o(v));
    atomicAdd(&deg[dst[e]], 1);
}

// ---- K4: ex1 = exp(s1-m1); den1 += ----
__global__ void k_ex1(const int* __restrict__ src, float* __restrict__ s1x,
                      const unsigned* __restrict__ m1, float* __restrict__ den1)
{
    int e = blockIdx.x * 256 + threadIdx.x;
    if (e >= NE) return;
    int s = src[e];
    float ex = expf(s1x[e] - o2f(m1[s]));
    s1x[e] = ex;
    atomicAdd(&den1[s], ex);
}

// ---- K4b: exclusive prefix scan of deg -> offs, cursor (single block, shfl) ----
__global__ __launch_bounds__(1024) void k_scan(const int* __restrict__ deg,
    int* __restrict__ offs, int* __restrict__ cursor)
{
    __shared__ int wsum[16];
    __shared__ int carry_s;
    int tid = threadIdx.x;
    int lane = tid & 63, wid = tid >> 6;
    if (tid == 0) carry_s = 0;
    __syncthreads();
    for (int base = 0; base < NN; base += 1024) {
        int idx = base + tid;
        int v = (idx < NN) ? deg[idx] : 0;
        int x = v;
        #pragma unroll
        for (int off = 1; off < 64; off <<= 1) {
            int t = __shfl_up(x, off);
            if (lane >= off) x += t;
        }
        if (lane == 63) wsum[wid] = x;
        __syncthreads();
        if (wid == 0) {
            int s = (lane < 16) ? wsum[lane] : 0;
            #pragma unroll
            for (int off = 1; off < 16; off <<= 1) {
                int t = __shfl_up(s, off);
                if (lane >= off) s += t;
            }
            if (lane < 16) wsum[lane] = s;
        }
        __syncthreads();
        int wbase = (wid > 0) ? wsum[wid - 1] : 0;
        int incl = x + wbase;
        int carry = carry_s;
        if (idx < NN) {
            int excl = carry + incl - v;
            offs[idx] = excl;
            cursor[idx] = excl;
        }
        __syncthreads();
        if (tid == 1023) carry_s = carry + incl;
        __syncthreads();
    }
    if (tid == 0) offs[NN] = carry_s;
}

// ---- K5: gamma; s2; segment max over dst; CSR bucket fill ----
__global__ void k_gamma_s2(const int* __restrict__ src, const int* __restrict__ dst,
    const float* __restrict__ s1x, const float* __restrict__ den1,
    const float* __restrict__ c2, const float* __restrict__ b_src, const float* __restrict__ b_dst,
    float* __restrict__ gamma, float* __restrict__ s2x, unsigned* __restrict__ m2,
    int* __restrict__ cursor, int* __restrict__ eidx)
{
    int e = blockIdx.x * 256 + threadIdx.x;
    if (e >= NE) return;
    int s = src[e], t = dst[e];
    float g = s1x[e] / den1[s];
    gamma[e] = g;
    float v = lrelu(b_src[s] + g * c2[e] + b_dst[t]);
    s2x[e] = v;
    atomicMax(&m2[t], f2o(v));
    int pos = atomicAdd(&cursor[t], 1);
    eidx[pos] = e;
}

// ---- K6: ex2 = exp(s2-m2); den2 += ----
__global__ void k_ex2(const int* __restrict__ dst, float* __restrict__ s2x,
                      const unsigned* __restrict__ m2, float* __restrict__ den2)
{
    int e = blockIdx.x * 256 + threadIdx.x;
    if (e >= NE) return;
    int t = dst[e];
    float ex = expf(s2x[e] - o2f(m2[t]));
    s2x[e] = ex;
    atomicAdd(&den2[t], ex);
}

// ---- K7: alpha store + e_w scale (in place) + zphi per-type reduction ----
// 32 lanes per edge, 2 edges in flight per group for ILP.
__global__ __launch_bounds__(256) void k_zphi(const int* __restrict__ src, const int* __restrict__ dst,
    const int* __restrict__ ety, const float* __restrict__ s2x, const float* __restrict__ den2,
    const float* __restrict__ gamma, const float* __restrict__ z, float* __restrict__ ew,
    float* __restrict__ alpha, float* __restrict__ zphi)
{
    __shared__ float zl[512];
    int tid = threadIdx.x;
    zl[tid] = 0.f; zl[tid + 256] = 0.f;
    __syncthreads();
    int lane = tid & 31;
    int grp = tid >> 5;
    int d0 = lane * 4;
    float4 a0 = make_float4(0, 0, 0, 0), a1 = a0, a2 = a0, a3 = a0;
    int G = gridDim.x * 8;
    for (int e = blockIdx.x * 8 + grp; e < NE; e += 2 * G) {
        int e2 = e + G;
        bool h2 = e2 < NE;
        // issue both edges' metadata loads up front (independent chains)
        int dnA = dst[e];
        int srA = src[e];
        int tA  = ety[e];
        float sA = s2x[e];
        float gA = gamma[e];
        int dnB = 0, srB = 0, tB = 0; float sB = 0.f, gB = 0.f;
        if (h2) { dnB = dst[e2]; srB = src[e2]; tB = ety[e2]; sB = s2x[e2]; gB = gamma[e2]; }
        float dA = den2[dnA];
        float dB = h2 ? den2[dnB] : 1.f;
        float alA = sA / dA;
        float alB = sB / dB;
        if (lane == 0) { alpha[e] = alA; if (h2) alpha[e2] = alB; }
        // gathers
        float4 mA, mB = make_float4(0, 0, 0, 0);
        if (lane < 8) {
            mA = *(const float4*)&z[(size_t)srA * 32 + d0];
            if (h2) mB = *(const float4*)&z[(size_t)srB * 32 + d0];
        } else if (lane < 24) {
            float4 rA = *(const float4*)&ew[(size_t)e * 64 + (d0 - 32)];
            mA.x = gA * rA.x; mA.y = gA * rA.y; mA.z = gA * rA.z; mA.w = gA * rA.w;
            *(float4*)&ew[(size_t)e * 64 + (d0 - 32)] = mA;
            if (h2) {
                float4 rB = *(const float4*)&ew[(size_t)e2 * 64 + (d0 - 32)];
                mB.x = gB * rB.x; mB.y = gB * rB.y; mB.z = gB * rB.z; mB.w = gB * rB.w;
                *(float4*)&ew[(size_t)e2 * 64 + (d0 - 32)] = mB;
            }
        } else {
            mA = *(const float4*)&z[(size_t)dnA * 32 + (d0 - 96)];
            if (h2) mB = *(const float4*)&z[(size_t)dnB * 32 + (d0 - 96)];
        }
        float wA0 = (tA == 0) ? alA : 0.f, wA1 = (tA == 1) ? alA : 0.f;
        float wA2 = (tA == 2) ? alA : 0.f, wA3 = (tA == 3) ? alA : 0.f;
        float wB0 = (h2 && tB == 0) ? alB : 0.f, wB1 = (h2 && tB == 1) ? alB : 0.f;
        float wB2 = (h2 && tB == 2) ? alB : 0.f, wB3 = (h2 && tB == 3) ? alB : 0.f;
        a0.x += wA0 * mA.x + wB0 * mB.x; a0.y += wA0 * mA.y + wB0 * mB.y;
        a0.z += wA0 * mA.z + wB0 * mB.z; a0.w += wA0 * mA.w + wB0 * mB.w;
        a1.x += wA1 * mA.x + wB1 * mB.x; a1.y += wA1 * mA.y + wB1 * mB.y;
        a1.z += wA1 * mA.z + wB1 * mB.z; a1.w += wA1 * mA.w + wB1 * mB.w;
        a2.x += wA2 * mA.x + wB2 * mB.x; a2.y += wA2 * mA.y + wB2 * mB.y;
        a2.z += wA2 * mA.z + wB2 * mB.z; a2.w += wA2 * mA.w + wB2 * mB.w;
        a3.x += wA3 * mA.x + wB3 * mB.x; a3.y += wA3 * mA.y + wB3 * mB.y;
        a3.z += wA3 * mA.z + wB3 * mB.z; a3.w += wA3 * mA.w + wB3 * mB.w;
    }
    atomicAdd(&zl[0 * 128 + d0 + 0], a0.x); atomicAdd(&zl[0 * 128 + d0 + 1], a0.y);
    atomicAdd(&zl[0 * 128 + d0 + 2], a0.z); atomicAdd(&zl[0 * 128 + d0 + 3], a0.w);
    atomicAdd(&zl[1 * 128 + d0 + 0], a1.x); atomicAdd(&zl[1 * 128 + d0 + 1], a1.y);
    atomicAdd(&zl[1 * 128 + d0 + 2], a1.z); atomicAdd(&zl[1 * 128 + d0 + 3], a1.w);
    atomicAdd(&zl[2 * 128 + d0 + 0], a2.x); atomicAdd(&zl[2 * 128 + d0 + 1], a2.y);
    atomicAdd(&zl[2 * 128 + d0 + 2], a2.z); atomicAdd(&zl[2 * 128 + d0 + 3], a2.w);
    atomicAdd(&zl[3 * 128 + d0 + 0], a3.x); atomicAdd(&zl[3 * 128 + d0 + 1], a3.y);
    atomicAdd(&zl[3 * 128 + d0 + 2], a3.z); atomicAdd(&zl[3 * 128 + d0 + 3], a3.w);
    __syncthreads();
    atomicAdd(&zphi[tid], zl[tid]);
    atomicAdd(&zphi[tid + 256], zl[tid + 256]);
}

// ---- K8: beta = softmax(lrelu(zphi @ w_sem)) ----
__global__ __launch_bounds__(128) void k_beta(const float* __restrict__ zphi,
    const float* __restrict__ w_sem, float* __restrict__ beta)
{
    int tid = threadIdx.x;
    float w = w_sem[tid];
    float p0 = zphi[tid] * w, p1 = zphi[128 + tid] * w;
    float p2 = zphi[256 + tid] * w, p3 = zphi[384 + tid] * w;
    #pragma unroll
    for (int m = 32; m >= 1; m >>= 1) {
        p0 += __shfl_xor(p0, m); p1 += __shfl_xor(p1, m);
        p2 += __shfl_xor(p2, m); p3 += __shfl_xor(p3, m);
    }
    __shared__ float s[2][4];
    if ((tid & 63) == 0) {
        int w_ = tid >> 6;
        s[w_][0] = p0; s[w_][1] = p1; s[w_][2] = p2; s[w_][3] = p3;
    }
    __syncthreads();
    if (tid == 0) {
        float d0 = lrelu(s[0][0] + s[1][0]);
        float d1 = lrelu(s[0][1] + s[1][1]);
        float d2 = lrelu(s[0][2] + s[1][2]);
        float d3 = lrelu(s[0][3] + s[1][3]);
        float mx = fmaxf(fmaxf(d0, d1), fmaxf(d2, d3));
        float e0 = expf(d0 - mx), e1 = expf(d1 - mx), e2 = expf(d2 - mx), e3 = expf(d3 - mx);
        float inv = 1.f / (e0 + e1 + e2 + e3);
        beta[0] = e0 * inv; beta[1] = e1 * inv; beta[2] = e2 * inv; beta[3] = e3 * inv;
    }
}

// ---- K9: CSR scatter — one 32-lane group per node, no atomics, 2-way unroll ----
__global__ __launch_bounds__(256) void k_scatter(const int* __restrict__ offs,
    const int* __restrict__ eidx, const int* __restrict__ src, const int* __restrict__ ety,
    const float* __restrict__ alpha, const float* __restrict__ beta,
    const float* __restrict__ z, const float* __restrict__ ew, float* __restrict__ hbeta)
{
    int tid = threadIdx.x;
    int lane = tid & 31;
    int grp = tid >> 5;
    int n = blockIdx.x * 8 + grp;
    if (n >= NN) return;
    int d0 = lane * 4;
    int beg = offs[n], end = offs[n + 1];
    float b0 = beta[0], b1 = beta[1], b2 = beta[2], b3 = beta[3];
    float4 acc = make_float4(0, 0, 0, 0);
    float sumw = 0.f;
    int i = beg;
    for (; i + 2 <= end; i += 2) {
        int ea = eidx[i], eb = eidx[i + 1];
        int ta = ety[ea], tb = ety[eb];
        int sa = src[ea], sb = src[eb];
        float wa = alpha[ea] * (ta == 0 ? b0 : ta == 1 ? b1 : ta == 2 ? b2 : b3);
        float wb = alpha[eb] * (tb == 0 ? b0 : tb == 1 ? b1 : tb == 2 ? b2 : b3);
        sumw += wa + wb;
        if (lane < 24) {
            const float* pa = (lane < 8) ? &z[(size_t)sa * 32 + d0]
                                         : &ew[(size_t)ea * 64 + (d0 - 32)];
            const float* pb = (lane < 8) ? &z[(size_t)sb * 32 + d0]
                                         : &ew[(size_t)eb * 64 + (d0 - 32)];
            float4 ma = *(const float4*)pa;
            float4 mb = *(const float4*)pb;
            acc.x += wa * ma.x + wb * mb.x; acc.y += wa * ma.y + wb * mb.y;
            acc.z += wa * ma.z + wb * mb.z; acc.w += wa * ma.w + wb * mb.w;
        }
    }
    if (i < end) {
        int ea = eidx[i];
        int ta = ety[ea];
        int sa = src[ea];
        float wa = alpha[ea] * (ta == 0 ? b0 : ta == 1 ? b1 : ta == 2 ? b2 : b3);
        sumw += wa;
        if (lane < 24) {
            const float* pa = (lane < 8) ? &z[(size_t)sa * 32 + d0]
                                         : &ew[(size_t)ea * 64 + (d0 - 32)];
            float4 ma = *(const float4*)pa;
            acc.x += wa * ma.x; acc.y += wa * ma.y; acc.z += wa * ma.z; acc.w += wa * ma.w;
        }
    }
    if (lane >= 24) {
        float4 zd = *(const float4*)&z[(size_t)n * 32 + (d0 - 96)];
        acc.x = sumw * zd.x; acc.y = sumw * zd.y; acc.z = sumw * zd.z; acc.w = sumw * zd.w;
    }
    *(float4*)&hbeta[(size_t)n * 128 + d0] = acc;
}

// ---- K10: Z = hbeta @ W_fc2 ----
__global__ __launch_bounds__(256) void k_fc(const float* __restrict__ hb,
    const float* __restrict__ W, float* __restrict__ Z)
{
    __shared__ float hl[32 * 132];
    __shared__ float Wl[128 * 64];
    int tid = threadIdx.x;
    int nb = blockIdx.x * 32;
    for (int i = tid; i < 1024; i += 256) {
        int row = i >> 5, kc = (i & 31) * 4;
        float4 v = make_float4(0.f, 0.f, 0.f, 0.f);
        if (nb + row < NN) v = *(const float4*)&hb[(size_t)(nb + row) * 128 + kc];
        *(float4*)&hl[row * 132 + kc] = v;
    }
    for (int half = 0; half < 2; ++half) {
        __syncthreads();
        for (int i = tid; i < 2048; i += 256) {
            int k = i >> 4, c = (i & 15) * 4;
            *(float4*)&Wl[k * 64 + c] = *(const float4*)&W[(size_t)k * 128 + half * 64 + c];
        }
        __syncthreads();
        int node = tid >> 3;
        int c0 = (tid & 7) * 8;
        float acc[8] = {0, 0, 0, 0, 0, 0, 0, 0};
        #pragma unroll 4
        for (int k = 0; k < 128; ++k) {
            float a = hl[node * 132 + k];
            const float* wr = &Wl[k * 64 + c0];
            #pragma unroll
            for (int j = 0; j < 8; ++j) acc[j] += a * wr[j];
        }
        int n = nb + node;
        if (n < NN) {
            float4 o1, o2;
            o1.x = acc[0]; o1.y = acc[1]; o1.z = acc[2]; o1.w = acc[3];
            o2.x = acc[4]; o2.y = acc[5]; o2.z = acc[6]; o2.w = acc[7];
            *(float4*)&Z[(size_t)n * 128 + half * 64 + c0] = o1;
            *(float4*)&Z[(size_t)n * 128 + half * 64 + c0 + 4] = o2;
        }
    }
}

extern "C" void kernel_launch(void* const* d_in, const int* in_sizes, int n_in,
                              void* d_out, int out_size, void* d_ws, size_t ws_size,
                              hipStream_t stream)
{
    const float* nf     = (const float*)d_in[0];
    const float* ef     = (const float*)d_in[1];
    const int*   src    = (const int*)d_in[2];
    const int*   dst    = (const int*)d_in[3];
    const int*   ety    = (const int*)d_in[4];
    const float* W_n    = (const float*)d_in[5];
    const float* W_e    = (const float*)d_in[6];
    const float* w_eattn= (const float*)d_in[7];
    const float* w_attn = (const float*)d_in[8];
    const float* w_sem  = (const float*)d_in[9];
    const float* W_fc2  = (const float*)d_in[10];

    float* out = (float*)d_out;
    float* Z   = out;
    float* ew  = out + (size_t)NN * OUTD;

    float* ws    = (float*)d_ws;
    float* z     = ws + OFF_Z;
    float* a_src = ws + OFF_ASRC;
    float* b_src = ws + OFF_BSRC;
    float* b_dst = ws + OFF_BDST;
    float* c1    = ws + OFF_C1;
    float* c2    = ws + OFF_C2;
    float* s1x   = ws + OFF_S1X;
    float* gamma = ws + OFF_GAMMA;
    float* s2x   = ws + OFF_S2X;
    float* alpha = ws + OFF_ALPHA;
    unsigned* m1 = (unsigned*)(ws + OFF_M1);
    float* den1  = ws + OFF_DEN1;
    unsigned* m2 = (unsigned*)(ws + OFF_M2);
    float* den2  = ws + OFF_DEN2;
    float* zphi  = ws + OFF_ZPHI;
    float* beta  = ws + OFF_BETA;
    int* deg     = (int*)(ws + OFF_DEG);
    int* offs    = (int*)(ws + OFF_OFFS);
    int* cursor  = (int*)(ws + OFF_CURSOR);
    int* eidx    = (int*)(ws + OFF_EIDX);
    float* hbeta = ws + OFF_HBETA;

    // zero: m1, den1, m2, den2, zphi, beta, deg (contiguous, ~500 KB)
    hipMemsetAsync(ws + OFF_M1, 0, (size_t)(OFF_OFFS - OFF_M1) * 4, stream);

    k_node<<<NN / 8, 256, 0, stream>>>(nf, W_n, w_eattn, w_attn, z, a_src, b_src, b_dst);
    k_edge<<<NE / 16, 256, 0, stream>>>(ef, W_e, w_eattn, w_attn, ew, c1, c2);
    int gE = (NE + 255) / 256;
    k_s1<<<gE, 256, 0, stream>>>(c1, a_src, src, dst, s1x, m1, deg);
    k_ex1<<<gE, 256, 0, stream>>>(src, s1x, m1, den1);
    k_scan<<<1, 1024, 0, stream>>>(deg, offs, cursor);
    k_gamma_s2<<<gE, 256, 0, stream>>>(src, dst, s1x, den1, c2, b_src, b_dst, gamma, s2x, m2, cursor, eidx);
    k_ex2<<<gE, 256, 0, stream>>>(dst, s2x, m2, den2);
    k_zphi<<<2048, 256, 0, stream>>>(src, dst, ety, s2x, den2, gamma, z, ew, alpha, zphi);
    k_beta<<<1, 128, 0, stream>>>(zphi, w_sem, beta);
    k_scatter<<<(NN + 7) / 8, 256, 0, stream>>>(offs, eidx, src, ety, alpha, beta, z, ew, hbeta);
    k_fc<<<(NN + 31) / 32, 256, 0, stream>>>(hbeta, W_fc2, Z);
}

// Round 6
// 384.436 us; speedup vs baseline: 2.7799x; 1.2309x over previous
//
#include <hip/hip_runtime.h>

#define NN 25000
#define NE 400000
#define TT 4
#define NO 32
#define EO 64
#define DD 128
#define OUTD 128
#define ZGRID 2048

// ws offsets (in floats)
#define OFF_Z      0
#define OFF_ASRC   800000
#define OFF_BSRC   825000
#define OFF_BDST   850000
#define OFF_C1     875000     // aliased by zpart (ZGRID*256=524288 <= 800000 spanning c1+c2)
#define OFF_C2     1275000
#define OFF_S1X    1675000    // aliased by alpha after k_g2ex
#define OFF_GAMMA  2075000    // aliased by w after k_zphi_stream
#define OFF_S2X    2475000
// ---- memset zone [OFF_DEN1, OFF_OFFS) ----
#define OFF_DEN1   2875000
#define OFF_DEN2   2900000
#define OFF_ZPHI   2925000
#define OFF_BETA   2925512
#define OFF_CSRC   2926000
#define OFF_CDST   3026000
#define OFF_DEG    3126000
// ---- end memset zone ----
#define OFF_OFFS   3151000
#define OFF_CURSOR 3176004
#define OFF_EIDX   3201004
#define OFF_HBETA  3601004
#define WS_FLOATS  6801004

__device__ __forceinline__ float lrelu(float x) { return x > 0.f ? x : 0.01f * x; }

// ---- K1: z = nf @ W_n ; per-node scalars a_src, b_src, b_dst ----
__global__ __launch_bounds__(256) void k_node(const float* __restrict__ nf,
    const float* __restrict__ W_n, const float* __restrict__ w_eattn,
    const float* __restrict__ w_attn, float* __restrict__ z,
    float* __restrict__ a_src, float* __restrict__ b_src, float* __restrict__ b_dst)
{
    __shared__ float Wl[128 * 32];
    __shared__ float nl[8 * 128];
    int tid = threadIdx.x;
    for (int i = tid; i < 128 * 32 / 4; i += 256)
        ((float4*)Wl)[i] = ((const float4*)W_n)[i];
    int nb = blockIdx.x * 8;
    ((float4*)nl)[tid] = ((const float4*)(nf + (size_t)nb * 128))[tid];
    __syncthreads();
    int node = tid >> 5;
    int col = tid & 31;
    float acc = 0.f;
    #pragma unroll 8
    for (int k = 0; k < 128; ++k)
        acc += nl[node * 128 + k] * Wl[k * 32 + col];
    int n = nb + node;
    z[(size_t)n * 32 + col] = acc;
    float va = acc * w_eattn[64 + col];
    float vb = acc * w_attn[col];
    float vc = acc * w_attn[96 + col];
    #pragma unroll
    for (int m = 16; m >= 1; m >>= 1) {
        va += __shfl_xor(va, m);
        vb += __shfl_xor(vb, m);
        vc += __shfl_xor(vc, m);
    }
    if (col == 0) { a_src[n] = va; b_src[n] = vb; b_dst[n] = vc; }
}

// ---- K2: e_ft = ef @ W_e (RAW, written to out e_w region); c1, c2 ----
__global__ __launch_bounds__(256) void k_edge(const float* __restrict__ ef,
    const float* __restrict__ W_e, const float* __restrict__ w_eattn,
    const float* __restrict__ w_attn, float* __restrict__ eft_out,
    float* __restrict__ c1, float* __restrict__ c2)
{
    __shared__ float Wl[64 * 64];
    __shared__ float el[16 * 65];
    int tid = threadIdx.x;
    for (int i = tid; i < 64 * 64 / 4; i += 256)
        ((float4*)Wl)[i] = ((const float4*)W_e)[i];
    size_t eb = (size_t)blockIdx.x * 16;
    {
        float4 v = ((const float4*)(ef + eb * 64))[tid];
        int r = (tid * 4) / 64, k0 = (tid * 4) % 64;
        el[r * 65 + k0] = v.x; el[r * 65 + k0 + 1] = v.y;
        el[r * 65 + k0 + 2] = v.z; el[r * 65 + k0 + 3] = v.w;
    }
    __syncthreads();
    int ein = tid >> 4;
    int c0 = (tid & 15) * 4;
    float a0 = 0, a1 = 0, a2 = 0, a3 = 0;
    #pragma unroll 4
    for (int k = 0; k < 64; ++k) {
        float a = el[ein * 65 + k];
        const float* wr = &Wl[k * 64 + c0];
        a0 += a * wr[0]; a1 += a * wr[1]; a2 += a * wr[2]; a3 += a * wr[3];
    }
    size_t e = eb + ein;
    float4 o; o.x = a0; o.y = a1; o.z = a2; o.w = a3;
    ((float4*)(eft_out + e * 64))[c0 >> 2] = o;
    float p1 = a0 * w_eattn[c0] + a1 * w_eattn[c0 + 1] + a2 * w_eattn[c0 + 2] + a3 * w_eattn[c0 + 3];
    float p2 = a0 * w_attn[32 + c0] + a1 * w_attn[33 + c0] + a2 * w_attn[34 + c0] + a3 * w_attn[35 + c0];
    #pragma unroll
    for (int m = 8; m >= 1; m >>= 1) {
        p1 += __shfl_xor(p1, m);
        p2 += __shfl_xor(p2, m);
    }
    if ((tid & 15) == 0) { c1[e] = p1; c2[e] = p2; }
}

// ---- K3: ex1 = exp(lrelu(c1 + a_src[src])); den1 +=; deg histogram ----
__global__ void k_s1ex(const float* __restrict__ c1, const float* __restrict__ a_src,
                       const int* __restrict__ src, const int* __restrict__ dst,
                       float* __restrict__ s1x, float* __restrict__ den1, int* __restrict__ deg)
{
    int e = blockIdx.x * 256 + threadIdx.x;
    if (e >= NE) return;
    int s = src[e];
    float ex = expf(lrelu(c1[e] + a_src[s]));
    s1x[e] = ex;
    atomicAdd(&den1[s], ex);
    atomicAdd(&deg[dst[e]], 1);
}

// ---- K4: exclusive prefix scan of deg -> offs, cursor (single block, shfl) ----
__global__ __launch_bounds__(1024) void k_scan(const int* __restrict__ deg,
    int* __restrict__ offs, int* __restrict__ cursor)
{
    __shared__ int wsum[16];
    __shared__ int carry_s;
    int tid = threadIdx.x;
    int lane = tid & 63, wid = tid >> 6;
    if (tid == 0) carry_s = 0;
    __syncthreads();
    for (int base = 0; base < NN; base += 1024) {
        int idx = base + tid;
        int v = (idx < NN) ? deg[idx] : 0;
        int x = v;
        #pragma unroll
        for (int off = 1; off < 64; off <<= 1) {
            int t = __shfl_up(x, off);
            if (lane >= off) x += t;
        }
        if (lane == 63) wsum[wid] = x;
        __syncthreads();
        if (wid == 0) {
            int s = (lane < 16) ? wsum[lane] : 0;
            #pragma unroll
            for (int off = 1; off < 16; off <<= 1) {
                int t = __shfl_up(s, off);
                if (lane >= off) s += t;
            }
            if (lane < 16) wsum[lane] = s;
        }
        __syncthreads();
        int wbase = (wid > 0) ? wsum[wid - 1] : 0;
        int incl = x + wbase;
        int carry = carry_s;
        if (idx < NN) {
            int excl = carry + incl - v;
            offs[idx] = excl;
            cursor[idx] = excl;
        }
        __syncthreads();
        if (tid == 1023) carry_s = carry + incl;
        __syncthreads();
    }
    if (tid == 0) offs[NN] = carry_s;
}

// ---- K5: gamma; ex2 = exp(lrelu(...)); den2 +=; CSR bucket fill ----
__global__ void k_g2ex(const int* __restrict__ src, const int* __restrict__ dst,
    const float* __restrict__ s1x, const float* __restrict__ den1,
    const float* __restrict__ c2, const float* __restrict__ b_src, const float* __restrict__ b_dst,
    float* __restrict__ gamma, float* __restrict__ s2x, float* __restrict__ den2,
    int* __restrict__ cursor, int* __restrict__ eidx)
{
    int e = blockIdx.x * 256 + threadIdx.x;
    if (e >= NE) return;
    int s = src[e], t = dst[e];
    float g = s1x[e] / den1[s];
    gamma[e] = g;
    float ex = expf(lrelu(b_src[s] + g * c2[e] + b_dst[t]));
    s2x[e] = ex;
    atomicAdd(&den2[t], ex);
    int pos = atomicAdd(&cursor[t], 1);
    eidx[pos] = e;
}

// ---- K6: streaming edge pass: alpha, e_w scale+write, csrc/cdst coeffs,
//          per-type middle-64-dim partial sums. 16 lanes/edge, 2-way unroll. ----
__global__ __launch_bounds__(256) void k_zphi_stream(const int* __restrict__ src,
    const int* __restrict__ dst, const int* __restrict__ ety,
    const float* __restrict__ s2x, const float* __restrict__ den2,
    const float* __restrict__ gamma, float* __restrict__ ew, float* __restrict__ alpha,
    float* __restrict__ csrc, float* __restrict__ cdst, float* __restrict__ zpart)
{
    __shared__ float zl[256];
    int tid = threadIdx.x;
    zl[tid] = 0.f;
    __syncthreads();
    int sub = tid & 15, grp = tid >> 4;
    int d0 = sub * 4;
    float4 a0 = make_float4(0, 0, 0, 0), a1 = a0, a2 = a0, a3 = a0;
    int G = ZGRID * 16;
    for (int e = blockIdx.x * 16 + grp; e < NE; e += 2 * G) {
        int e2 = e + G;
        bool h2 = e2 < NE;
        int dnA = dst[e];   float sA = s2x[e];  float gA = gamma[e];  int tA = ety[e];
        int dnB = 0; float sB = 0.f, gB = 0.f; int tB = 0;
        if (h2) { dnB = dst[e2]; sB = s2x[e2]; gB = gamma[e2]; tB = ety[e2]; }
        float alA = sA / den2[dnA];
        float alB = h2 ? sB / den2[dnB] : 0.f;
        if (sub == 0) { alpha[e] = alA; if (h2) alpha[e2] = alB; }
        if (sub == 1) {
            atomicAdd(&csrc[src[e] * 4 + tA], alA);
            if (h2) atomicAdd(&csrc[src[e2] * 4 + tB], alB);
        }
        if (sub == 2) {
            atomicAdd(&cdst[dnA * 4 + tA], alA);
            if (h2) atomicAdd(&cdst[dnB * 4 + tB], alB);
        }
        float4 rA = *(const float4*)&ew[(size_t)e * 64 + d0];
        float4 mA; mA.x = gA * rA.x; mA.y = gA * rA.y; mA.z = gA * rA.z; mA.w = gA * rA.w;
        *(float4*)&ew[(size_t)e * 64 + d0] = mA;
        float4 mB = make_float4(0, 0, 0, 0);
        if (h2) {
            float4 rB = *(const float4*)&ew[(size_t)e2 * 64 + d0];
            mB.x = gB * rB.x; mB.y = gB * rB.y; mB.z = gB * rB.z; mB.w = gB * rB.w;
            *(float4*)&ew[(size_t)e2 * 64 + d0] = mB;
        }
        float wA0 = (tA == 0) ? alA : 0.f, wA1 = (tA == 1) ? alA : 0.f;
        float wA2 = (tA == 2) ? alA : 0.f, wA3 = (tA == 3) ? alA : 0.f;
        float wB0 = (h2 && tB == 0) ? alB : 0.f, wB1 = (h2 && tB == 1) ? alB : 0.f;
        float wB2 = (h2 && tB == 2) ? alB : 0.f, wB3 = (h2 && tB == 3) ? alB : 0.f;
        a0.x += wA0 * mA.x + wB0 * mB.x; a0.y += wA0 * mA.y + wB0 * mB.y;
        a0.z += wA0 * mA.z + wB0 * mB.z; a0.w += wA0 * mA.w + wB0 * mB.w;
        a1.x += wA1 * mA.x + wB1 * mB.x; a1.y += wA1 * mA.y + wB1 * mB.y;
        a1.z += wA1 * mA.z + wB1 * mB.z; a1.w += wA1 * mA.w + wB1 * mB.w;
        a2.x += wA2 * mA.x + wB2 * mB.x; a2.y += wA2 * mA.y + wB2 * mB.y;
        a2.z += wA2 * mA.z + wB2 * mB.z; a2.w += wA2 * mA.w + wB2 * mB.w;
        a3.x += wA3 * mA.x + wB3 * mB.x; a3.y += wA3 * mA.y + wB3 * mB.y;
        a3.z += wA3 * mA.z + wB3 * mB.z; a3.w += wA3 * mA.w + wB3 * mB.w;
    }
    // reduce over the 4 groups within each wave (lanes with same sub)
    #pragma unroll
    for (int m = 16; m <= 32; m <<= 1) {
        a0.x += __shfl_xor(a0.x, m); a0.y += __shfl_xor(a0.y, m);
        a0.z += __shfl_xor(a0.z, m); a0.w += __shfl_xor(a0.w, m);
        a1.x += __shfl_xor(a1.x, m); a1.y += __shfl_xor(a1.y, m);
        a1.z += __shfl_xor(a1.z, m); a1.w += __shfl_xor(a1.w, m);
        a2.x += __shfl_xor(a2.x, m); a2.y += __shfl_xor(a2.y, m);
        a2.z += __shfl_xor(a2.z, m); a2.w += __shfl_xor(a2.w, m);
        a3.x += __shfl_xor(a3.x, m); a3.y += __shfl_xor(a3.y, m);
        a3.z += __shfl_xor(a3.z, m); a3.w += __shfl_xor(a3.w, m);
    }
    if ((tid & 63) < 16) {
        atomicAdd(&zl[0 * 64 + d0 + 0], a0.x); atomicAdd(&zl[0 * 64 + d0 + 1], a0.y);
        atomicAdd(&zl[0 * 64 + d0 + 2], a0.z); atomicAdd(&zl[0 * 64 + d0 + 3], a0.w);
        atomicAdd(&zl[1 * 64 + d0 + 0], a1.x); atomicAdd(&zl[1 * 64 + d0 + 1], a1.y);
        atomicAdd(&zl[1 * 64 + d0 + 2], a1.z); atomicAdd(&zl[1 * 64 + d0 + 3], a1.w);
        atomicAdd(&zl[2 * 64 + d0 + 0], a2.x); atomicAdd(&zl[2 * 64 + d0 + 1], a2.y);
        atomicAdd(&zl[2 * 64 + d0 + 2], a2.z); atomicAdd(&zl[2 * 64 + d0 + 3], a2.w);
        atomicAdd(&zl[3 * 64 + d0 + 0], a3.x); atomicAdd(&zl[3 * 64 + d0 + 1], a3.y);
        atomicAdd(&zl[3 * 64 + d0 + 2], a3.z); atomicAdd(&zl[3 * 64 + d0 + 3], a3.w);
    }
    __syncthreads();
    zpart[(size_t)blockIdx.x * 256 + tid] = zl[tid];
}

// ---- K6b: reduce zpart -> zphi middle dims (deterministic two-stage) ----
__global__ __launch_bounds__(256) void k_zphi_red(const float* __restrict__ zpart,
    float* __restrict__ zphi)
{
    int tid = threadIdx.x;
    float s = 0.f;
    int r0 = blockIdx.x * 32;
    for (int r = r0; r < r0 + 32; ++r)
        s += zpart[(size_t)r * 256 + tid];
    atomicAdd(&zphi[(tid >> 6) * 128 + 32 + (tid & 63)], s);
}

// ---- K6c: zphi z-parts from per-node coefficients: sum csrc/cdst[n][t]*z[n] ----
__global__ __launch_bounds__(256) void k_zphi_nodes(const float* __restrict__ z,
    const float* __restrict__ csrc, const float* __restrict__ cdst, float* __restrict__ zphi)
{
    __shared__ float zl[256];
    int tid = threadIdx.x;
    zl[tid] = 0.f;
    __syncthreads();
    int d = tid & 31, ng = tid >> 5;
    float s0 = 0, s1 = 0, s2 = 0, s3 = 0, t0 = 0, t1 = 0, t2 = 0, t3 = 0;
    for (int n = blockIdx.x * 8 + ng; n < NN; n += gridDim.x * 8) {
        float zv = z[(size_t)n * 32 + d];
        float4 cs = *(const float4*)&csrc[n * 4];
        float4 cd = *(const float4*)&cdst[n * 4];
        s0 += cs.x * zv; s1 += cs.y * zv; s2 += cs.z * zv; s3 += cs.w * zv;
        t0 += cd.x * zv; t1 += cd.y * zv; t2 += cd.z * zv; t3 += cd.w * zv;
    }
    s0 += __shfl_xor(s0, 32); s1 += __shfl_xor(s1, 32);
    s2 += __shfl_xor(s2, 32); s3 += __shfl_xor(s3, 32);
    t0 += __shfl_xor(t0, 32); t1 += __shfl_xor(t1, 32);
    t2 += __shfl_xor(t2, 32); t3 += __shfl_xor(t3, 32);
    if ((tid & 63) < 32) {
        atomicAdd(&zl[0 * 32 + d], s0); atomicAdd(&zl[1 * 32 + d], s1);
        atomicAdd(&zl[2 * 32 + d], s2); atomicAdd(&zl[3 * 32 + d], s3);
        atomicAdd(&zl[128 + 0 * 32 + d], t0); atomicAdd(&zl[128 + 1 * 32 + d], t1);
        atomicAdd(&zl[128 + 2 * 32 + d], t2); atomicAdd(&zl[128 + 3 * 32 + d], t3);
    }
    __syncthreads();
    if (tid < 128) atomicAdd(&zphi[(tid >> 5) * 128 + (tid & 31)], zl[tid]);
    else atomicAdd(&zphi[((tid - 128) >> 5) * 128 + 96 + (tid & 31)], zl[tid]);
}

// ---- K7: beta = softmax(lrelu(zphi @ w_sem)) ----
__global__ __launch_bounds__(128) void k_beta(const float* __restrict__ zphi,
    const float* __restrict__ w_sem, float* __restrict__ beta)
{
    int tid = threadIdx.x;
    float w = w_sem[tid];
    float p0 = zphi[tid] * w, p1 = zphi[128 + tid] * w;
    float p2 = zphi[256 + tid] * w, p3 = zphi[384 + tid] * w;
    #pragma unroll
    for (int m = 32; m >= 1; m >>= 1) {
        p0 += __shfl_xor(p0, m); p1 += __shfl_xor(p1, m);
        p2 += __shfl_xor(p2, m); p3 += __shfl_xor(p3, m);
    }
    __shared__ float s[2][4];
    if ((tid & 63) == 0) {
        int w_ = tid >> 6;
        s[w_][0] = p0; s[w_][1] = p1; s[w_][2] = p2; s[w_][3] = p3;
    }
    __syncthreads();
    if (tid == 0) {
        float d0 = lrelu(s[0][0] + s[1][0]);
        float d1 = lrelu(s[0][1] + s[1][1]);
        float d2 = lrelu(s[0][2] + s[1][2]);
        float d3 = lrelu(s[0][3] + s[1][3]);
        float mx = fmaxf(fmaxf(d0, d1), fmaxf(d2, d3));
        float e0 = expf(d0 - mx), e1 = expf(d1 - mx), e2 = expf(d2 - mx), e3 = expf(d3 - mx);
        float inv = 1.f / (e0 + e1 + e2 + e3);
        beta[0] = e0 * inv; beta[1] = e1 * inv; beta[2] = e2 * inv; beta[3] = e3 * inv;
    }
}

// ---- K8: w[e] = alpha[e] * beta[ety[e]] ----
__global__ void k_walpha(const float* __restrict__ alpha, const int* __restrict__ ety,
                         const float* __restrict__ beta, float* __restrict__ w)
{
    int e = blockIdx.x * 256 + threadIdx.x;
    if (e >= NE) return;
    w[e] = alpha[e] * beta[ety[e]];
}

// ---- K9: CSR scatter — one 32-lane group per node, no atomics, 2-way unroll ----
__global__ __launch_bounds__(256) void k_scatter(const int* __restrict__ offs,
    const int* __restrict__ eidx, const int* __restrict__ src,
    const float* __restrict__ w, const float* __restrict__ z,
    const float* __restrict__ ew, float* __restrict__ hbeta)
{
    int tid = threadIdx.x;
    int lane = tid & 31;
    int grp = tid >> 5;
    int n = blockIdx.x * 8 + grp;
    if (n >= NN) return;
    int d0 = lane * 4;
    int beg = offs[n], end = offs[n + 1];
    float4 acc = make_float4(0, 0, 0, 0);
    float sumw = 0.f;
    int i = beg;
    for (; i + 2 <= end; i += 2) {
        int ea = eidx[i], eb = eidx[i + 1];
        float wa = w[ea], wb = w[eb];
        int sa = src[ea], sb = src[eb];
        sumw += wa + wb;
        if (lane < 24) {
            const float* pa = (lane < 8) ? &z[(size_t)sa * 32 + d0]
                                         : &ew[(size_t)ea * 64 + (d0 - 32)];
            const float* pb = (lane < 8) ? &z[(size_t)sb * 32 + d0]
                                         : &ew[(size_t)eb * 64 + (d0 - 32)];
            float4 ma = *(const float4*)pa;
            float4 mb = *(const float4*)pb;
            acc.x += wa * ma.x + wb * mb.x; acc.y += wa * ma.y + wb * mb.y;
            acc.z += wa * ma.z + wb * mb.z; acc.w += wa * ma.w + wb * mb.w;
        }
    }
    if (i < end) {
        int ea = eidx[i];
        float wa = w[ea];
        int sa = src[ea];
        sumw += wa;
        if (lane < 24) {
            const float* pa = (lane < 8) ? &z[(size_t)sa * 32 + d0]
                                         : &ew[(size_t)ea * 64 + (d0 - 32)];
            float4 ma = *(const float4*)pa;
            acc.x += wa * ma.x; acc.y += wa * ma.y; acc.z += wa * ma.z; acc.w += wa * ma.w;
        }
    }
    if (lane >= 24) {
        float4 zd = *(const float4*)&z[(size_t)n * 32 + (d0 - 96)];
        acc.x = sumw * zd.x; acc.y = sumw * zd.y; acc.z = sumw * zd.z; acc.w = sumw * zd.w;
    }
    *(float4*)&hbeta[(size_t)n * 128 + d0] = acc;
}

// ---- K10: Z = hbeta @ W_fc2 ----
__global__ __launch_bounds__(256) void k_fc(const float* __restrict__ hb,
    const float* __restrict__ W, float* __restrict__ Z)
{
    __shared__ float hl[32 * 132];
    __shared__ float Wl[128 * 64];
    int tid = threadIdx.x;
    int nb = blockIdx.x * 32;
    for (int i = tid; i < 1024; i += 256) {
        int row = i >> 5, kc = (i & 31) * 4;
        float4 v = make_float4(0.f, 0.f, 0.f, 0.f);
        if (nb + row < NN) v = *(const float4*)&hb[(size_t)(nb + row) * 128 + kc];
        *(float4*)&hl[row * 132 + kc] = v;
    }
    for (int half = 0; half < 2; ++half) {
        __syncthreads();
        for (int i = tid; i < 2048; i += 256) {
            int k = i >> 4, c = (i & 15) * 4;
            *(float4*)&Wl[k * 64 + c] = *(const float4*)&W[(size_t)k * 128 + half * 64 + c];
        }
        __syncthreads();
        int node = tid >> 3;
        int c0 = (tid & 7) * 8;
        float acc[8] = {0, 0, 0, 0, 0, 0, 0, 0};
        #pragma unroll 4
        for (int k = 0; k < 128; ++k) {
            float a = hl[node * 132 + k];
            const float* wr = &Wl[k * 64 + c0];
            #pragma unroll
            for (int j = 0; j < 8; ++j) acc[j] += a * wr[j];
        }
        int n = nb + node;
        if (n < NN) {
            float4 o1, o2;
            o1.x = acc[0]; o1.y = acc[1]; o1.z = acc[2]; o1.w = acc[3];
            o2.x = acc[4]; o2.y = acc[5]; o2.z = acc[6]; o2.w = acc[7];
            *(float4*)&Z[(size_t)n * 128 + half * 64 + c0] = o1;
            *(float4*)&Z[(size_t)n * 128 + half * 64 + c0 + 4] = o2;
        }
    }
}

extern "C" void kernel_launch(void* const* d_in, const int* in_sizes, int n_in,
                              void* d_out, int out_size, void* d_ws, size_t ws_size,
                              hipStream_t stream)
{
    const float* nf     = (const float*)d_in[0];
    const float* ef     = (const float*)d_in[1];
    const int*   src    = (const int*)d_in[2];
    const int*   dst    = (const int*)d_in[3];
    const int*   ety    = (const int*)d_in[4];
    const float* W_n    = (const float*)d_in[5];
    const float* W_e    = (const float*)d_in[6];
    const float* w_eattn= (const float*)d_in[7];
    const float* w_attn = (const float*)d_in[8];
    const float* w_sem  = (const float*)d_in[9];
    const float* W_fc2  = (const float*)d_in[10];

    float* out = (float*)d_out;
    float* Z   = out;
    float* ew  = out + (size_t)NN * OUTD;

    float* ws    = (float*)d_ws;
    float* z     = ws + OFF_Z;
    float* a_src = ws + OFF_ASRC;
    float* b_src = ws + OFF_BSRC;
    float* b_dst = ws + OFF_BDST;
    float* c1    = ws + OFF_C1;
    float* c2    = ws + OFF_C2;
    float* s1x   = ws + OFF_S1X;
    float* gamma = ws + OFF_GAMMA;
    float* s2x   = ws + OFF_S2X;
    float* alpha = ws + OFF_S1X;     // alias: s1x dead after k_g2ex
    float* wgt   = ws + OFF_GAMMA;   // alias: gamma dead after k_zphi_stream
    float* zpart = ws + OFF_C1;      // alias: c1/c2 dead after k_g2ex
    float* den1  = ws + OFF_DEN1;
    float* den2  = ws + OFF_DEN2;
    float* zphi  = ws + OFF_ZPHI;
    float* beta  = ws + OFF_BETA;
    float* csrc  = ws + OFF_CSRC;
    float* cdst  = ws + OFF_CDST;
    int* deg     = (int*)(ws + OFF_DEG);
    int* offs    = (int*)(ws + OFF_OFFS);
    int* cursor  = (int*)(ws + OFF_CURSOR);
    int* eidx    = (int*)(ws + OFF_EIDX);
    float* hbeta = ws + OFF_HBETA;

    // zero: den1, den2, zphi, beta, csrc, cdst, deg (contiguous, ~1.1 MB)
    hipMemsetAsync(ws + OFF_DEN1, 0, (size_t)(OFF_OFFS - OFF_DEN1) * 4, stream);

    k_node<<<NN / 8, 256, 0, stream>>>(nf, W_n, w_eattn, w_attn, z, a_src, b_src, b_dst);
    k_edge<<<NE / 16, 256, 0, stream>>>(ef, W_e, w_eattn, w_attn, ew, c1, c2);
    int gE = (NE + 255) / 256;
    k_s1ex<<<gE, 256, 0, stream>>>(c1, a_src, src, dst, s1x, den1, deg);
    k_scan<<<1, 1024, 0, stream>>>(deg, offs, cursor);
    k_g2ex<<<gE, 256, 0, stream>>>(src, dst, s1x, den1, c2, b_src, b_dst, gamma, s2x, den2, cursor, eidx);
    k_zphi_stream<<<ZGRID, 256, 0, stream>>>(src, dst, ety, s2x, den2, gamma, ew, alpha, csrc, cdst, zpart);
    k_zphi_red<<<ZGRID / 32, 256, 0, stream>>>(zpart, zphi);
    k_zphi_nodes<<<128, 256, 0, stream>>>(z, csrc, cdst, zphi);
    k_beta<<<1, 128, 0, stream>>>(zphi, w_sem, beta);
    k_walpha<<<gE, 256, 0, stream>>>(alpha, ety, beta, wgt);
    k_scatter<<<(NN + 7) / 8, 256, 0, stream>>>(offs, eidx, src, wgt, z, ew, hbeta);
    k_fc<<<(NN + 31) / 32, 256, 0, stream>>>(hbeta, W_fc2, Z);
}

// Round 7
// 350.742 us; speedup vs baseline: 3.0469x; 1.0961x over previous
//
#include <hip/hip_runtime.h>

#define NN 25000
#define NE 400000
#define TT 4
#define NO 32
#define EO 64
#define DD 128
#define OUTD 128
#define ZGRID 2048

// ws offsets (in floats)
#define OFF_Z      0
#define OFF_ASRC   800000
#define OFF_BSRC   825000
#define OFF_BDST   850000
#define OFF_C1     875000     // aliased by zpart (ZGRID*256=524288 <= 800000 spanning c1+c2)
#define OFF_C2     1275000
#define OFF_S1X    1675000    // aliased by alpha after k_g2ex
#define OFF_GAMMA  2075000    // aliased by w after k_zphi_stream
#define OFF_S2X    2475000
// ---- memset zone [OFF_DEN1, OFF_OFFS) ----
#define OFF_DEN1   2875000
#define OFF_DEN2   2900000
#define OFF_ZPHI   2925000
#define OFF_BETA   2925512
#define OFF_CSRC   2926000
#define OFF_CDST   3026000
#define OFF_DEG    3126000
// ---- end memset zone ----
#define OFF_OFFS   3151000
#define OFF_CURSOR 3176004
#define OFF_EIDX   3201004
#define OFF_HBETA  3601004
#define WS_FLOATS  6801004

__device__ __forceinline__ float lrelu(float x) { return x > 0.f ? x : 0.01f * x; }

// ---- K1: z = nf @ W_n ; per-node scalars a_src, b_src, b_dst ----
__global__ __launch_bounds__(256) void k_node(const float* __restrict__ nf,
    const float* __restrict__ W_n, const float* __restrict__ w_eattn,
    const float* __restrict__ w_attn, float* __restrict__ z,
    float* __restrict__ a_src, float* __restrict__ b_src, float* __restrict__ b_dst)
{
    __shared__ float Wl[128 * 32];
    __shared__ float nl[8 * 128];
    int tid = threadIdx.x;
    for (int i = tid; i < 128 * 32 / 4; i += 256)
        ((float4*)Wl)[i] = ((const float4*)W_n)[i];
    int nb = blockIdx.x * 8;
    ((float4*)nl)[tid] = ((const float4*)(nf + (size_t)nb * 128))[tid];
    __syncthreads();
    int node = tid >> 5;
    int col = tid & 31;
    float acc = 0.f;
    #pragma unroll 8
    for (int k = 0; k < 128; ++k)
        acc += nl[node * 128 + k] * Wl[k * 32 + col];
    int n = nb + node;
    z[(size_t)n * 32 + col] = acc;
    float va = acc * w_eattn[64 + col];
    float vb = acc * w_attn[col];
    float vc = acc * w_attn[96 + col];
    #pragma unroll
    for (int m = 16; m >= 1; m >>= 1) {
        va += __shfl_xor(va, m);
        vb += __shfl_xor(vb, m);
        vc += __shfl_xor(vc, m);
    }
    if (col == 0) { a_src[n] = va; b_src[n] = vb; b_dst[n] = vc; }
}

// ---- K2: e_ft = ef @ W_e (RAW, to out e_w region); c1, c2.
//      Register-blocked 4 edges x 4 cols per thread; 64 edges per block. ----
__global__ __launch_bounds__(256) void k_edge(const float* __restrict__ ef,
    const float* __restrict__ W_e, const float* __restrict__ w_eattn,
    const float* __restrict__ w_attn, float* __restrict__ eft_out,
    float* __restrict__ c1, float* __restrict__ c2)
{
    __shared__ float Wl[64 * 64];     // [k][c]
    __shared__ float el[64 * 68];     // [e][k], pitch 68 (16B-aligned rows)
    int tid = threadIdx.x;
    size_t eb = (size_t)blockIdx.x * 64;
    for (int i = tid; i < 1024; i += 256)
        ((float4*)Wl)[i] = ((const float4*)W_e)[i];
    for (int i = tid; i < 1024; i += 256) {
        int e = i >> 4, q = i & 15;
        float4 v = ((const float4*)(ef + (eb + e) * 64))[q];
        *(float4*)&el[e * 68 + q * 4] = v;
    }
    __syncthreads();
    int cgrp = tid & 15, egrp = tid >> 4;
    int c0 = cgrp * 4;
    int e0 = egrp * 4;
    float acc[4][4];
    #pragma unroll
    for (int i = 0; i < 4; ++i)
        #pragma unroll
        for (int j = 0; j < 4; ++j) acc[i][j] = 0.f;
    #pragma unroll 4
    for (int k0 = 0; k0 < 64; k0 += 4) {
        float4 a[4], w[4];
        #pragma unroll
        for (int e = 0; e < 4; ++e) a[e] = *(const float4*)&el[(e0 + e) * 68 + k0];
        #pragma unroll
        for (int j = 0; j < 4; ++j) w[j] = *(const float4*)&Wl[(k0 + j) * 64 + c0];
        #pragma unroll
        for (int e = 0; e < 4; ++e) {
            acc[e][0] += a[e].x * w[0].x + a[e].y * w[1].x + a[e].z * w[2].x + a[e].w * w[3].x;
            acc[e][1] += a[e].x * w[0].y + a[e].y * w[1].y + a[e].z * w[2].y + a[e].w * w[3].y;
            acc[e][2] += a[e].x * w[0].z + a[e].y * w[1].z + a[e].z * w[2].z + a[e].w * w[3].z;
            acc[e][3] += a[e].x * w[0].w + a[e].y * w[1].w + a[e].z * w[2].w + a[e].w * w[3].w;
        }
    }
    float4 we1 = *(const float4*)&w_eattn[c0];
    float4 we2 = *(const float4*)&w_attn[32 + c0];
    #pragma unroll
    for (int e = 0; e < 4; ++e) {
        float4 o; o.x = acc[e][0]; o.y = acc[e][1]; o.z = acc[e][2]; o.w = acc[e][3];
        *(float4*)&eft_out[(eb + e0 + e) * 64 + c0] = o;
        float p1 = o.x * we1.x + o.y * we1.y + o.z * we1.z + o.w * we1.w;
        float p2 = o.x * we2.x + o.y * we2.y + o.z * we2.z + o.w * we2.w;
        #pragma unroll
        for (int m = 8; m >= 1; m >>= 1) {
            p1 += __shfl_xor(p1, m);
            p2 += __shfl_xor(p2, m);
        }
        if (cgrp == 0) { c1[eb + e0 + e] = p1; c2[eb + e0 + e] = p2; }
    }
}

// ---- K3: ex1 = exp(lrelu(c1 + a_src[src])); den1 +=; deg histogram ----
__global__ void k_s1ex(const float* __restrict__ c1, const float* __restrict__ a_src,
                       const int* __restrict__ src, const int* __restrict__ dst,
                       float* __restrict__ s1x, float* __restrict__ den1, int* __restrict__ deg)
{
    int e = blockIdx.x * 256 + threadIdx.x;
    if (e >= NE) return;
    int s = src[e];
    float ex = expf(lrelu(c1[e] + a_src[s]));
    s1x[e] = ex;
    atomicAdd(&den1[s], ex);
    atomicAdd(&deg[dst[e]], 1);
}

// ---- K4: exclusive prefix scan of deg -> offs, cursor (single block, shfl) ----
__global__ __launch_bounds__(1024) void k_scan(const int* __restrict__ deg,
    int* __restrict__ offs, int* __restrict__ cursor)
{
    __shared__ int wsum[16];
    __shared__ int carry_s;
    int tid = threadIdx.x;
    int lane = tid & 63, wid = tid >> 6;
    if (tid == 0) carry_s = 0;
    __syncthreads();
    for (int base = 0; base < NN; base += 1024) {
        int idx = base + tid;
        int v = (idx < NN) ? deg[idx] : 0;
        int x = v;
        #pragma unroll
        for (int off = 1; off < 64; off <<= 1) {
            int t = __shfl_up(x, off);
            if (lane >= off) x += t;
        }
        if (lane == 63) wsum[wid] = x;
        __syncthreads();
        if (wid == 0) {
            int s = (lane < 16) ? wsum[lane] : 0;
            #pragma unroll
            for (int off = 1; off < 16; off <<= 1) {
                int t = __shfl_up(s, off);
                if (lane >= off) s += t;
            }
            if (lane < 16) wsum[lane] = s;
        }
        __syncthreads();
        int wbase = (wid > 0) ? wsum[wid - 1] : 0;
        int incl = x + wbase;
        int carry = carry_s;
        if (idx < NN) {
            int excl = carry + incl - v;
            offs[idx] = excl;
            cursor[idx] = excl;
        }
        __syncthreads();
        if (tid == 1023) carry_s = carry + incl;
        __syncthreads();
    }
    if (tid == 0) offs[NN] = carry_s;
}

// ---- K5: gamma; ex2 = exp(lrelu(...)); den2 +=; CSR bucket fill ----
__global__ void k_g2ex(const int* __restrict__ src, const int* __restrict__ dst,
    const float* __restrict__ s1x, const float* __restrict__ den1,
    const float* __restrict__ c2, const float* __restrict__ b_src, const float* __restrict__ b_dst,
    float* __restrict__ gamma, float* __restrict__ s2x, float* __restrict__ den2,
    int* __restrict__ cursor, int* __restrict__ eidx)
{
    int e = blockIdx.x * 256 + threadIdx.x;
    if (e >= NE) return;
    int s = src[e], t = dst[e];
    float g = s1x[e] / den1[s];
    gamma[e] = g;
    float ex = expf(lrelu(b_src[s] + g * c2[e] + b_dst[t]));
    s2x[e] = ex;
    atomicAdd(&den2[t], ex);
    int pos = atomicAdd(&cursor[t], 1);
    eidx[pos] = e;
}

// ---- K6: streaming edge pass: alpha, e_w scale+write, csrc/cdst coeffs,
//          per-type middle-64-dim partial sums. 16 lanes/edge, 2-way unroll. ----
__global__ __launch_bounds__(256) void k_zphi_stream(const int* __restrict__ src,
    const int* __restrict__ dst, const int* __restrict__ ety,
    const float* __restrict__ s2x, const float* __restrict__ den2,
    const float* __restrict__ gamma, float* __restrict__ ew, float* __restrict__ alpha,
    float* __restrict__ csrc, float* __restrict__ cdst, float* __restrict__ zpart)
{
    __shared__ float zl[256];
    int tid = threadIdx.x;
    zl[tid] = 0.f;
    __syncthreads();
    int sub = tid & 15, grp = tid >> 4;
    int d0 = sub * 4;
    float4 a0 = make_float4(0, 0, 0, 0), a1 = a0, a2 = a0, a3 = a0;
    int G = ZGRID * 16;
    for (int e = blockIdx.x * 16 + grp; e < NE; e += 2 * G) {
        int e2 = e + G;
        bool h2 = e2 < NE;
        int dnA = dst[e];   float sA = s2x[e];  float gA = gamma[e];  int tA = ety[e];
        int dnB = 0; float sB = 0.f, gB = 0.f; int tB = 0;
        if (h2) { dnB = dst[e2]; sB = s2x[e2]; gB = gamma[e2]; tB = ety[e2]; }
        float alA = sA / den2[dnA];
        float alB = h2 ? sB / den2[dnB] : 0.f;
        if (sub == 0) { alpha[e] = alA; if (h2) alpha[e2] = alB; }
        if (sub == 1) {
            atomicAdd(&csrc[src[e] * 4 + tA], alA);
            if (h2) atomicAdd(&csrc[src[e2] * 4 + tB], alB);
        }
        if (sub == 2) {
            atomicAdd(&cdst[dnA * 4 + tA], alA);
            if (h2) atomicAdd(&cdst[dnB * 4 + tB], alB);
        }
        float4 rA = *(const float4*)&ew[(size_t)e * 64 + d0];
        float4 mA; mA.x = gA * rA.x; mA.y = gA * rA.y; mA.z = gA * rA.z; mA.w = gA * rA.w;
        *(float4*)&ew[(size_t)e * 64 + d0] = mA;
        float4 mB = make_float4(0, 0, 0, 0);
        if (h2) {
            float4 rB = *(const float4*)&ew[(size_t)e2 * 64 + d0];
            mB.x = gB * rB.x; mB.y = gB * rB.y; mB.z = gB * rB.z; mB.w = gB * rB.w;
            *(float4*)&ew[(size_t)e2 * 64 + d0] = mB;
        }
        float wA0 = (tA == 0) ? alA : 0.f, wA1 = (tA == 1) ? alA : 0.f;
        float wA2 = (tA == 2) ? alA : 0.f, wA3 = (tA == 3) ? alA : 0.f;
        float wB0 = (h2 && tB == 0) ? alB : 0.f, wB1 = (h2 && tB == 1) ? alB : 0.f;
        float wB2 = (h2 && tB == 2) ? alB : 0.f, wB3 = (h2 && tB == 3) ? alB : 0.f;
        a0.x += wA0 * mA.x + wB0 * mB.x; a0.y += wA0 * mA.y + wB0 * mB.y;
        a0.z += wA0 * mA.z + wB0 * mB.z; a0.w += wA0 * mA.w + wB0 * mB.w;
        a1.x += wA1 * mA.x + wB1 * mB.x; a1.y += wA1 * mA.y + wB1 * mB.y;
        a1.z += wA1 * mA.z + wB1 * mB.z; a1.w += wA1 * mA.w + wB1 * mB.w;
        a2.x += wA2 * mA.x + wB2 * mB.x; a2.y += wA2 * mA.y + wB2 * mB.y;
        a2.z += wA2 * mA.z + wB2 * mB.z; a2.w += wA2 * mA.w + wB2 * mB.w;
        a3.x += wA3 * mA.x + wB3 * mB.x; a3.y += wA3 * mA.y + wB3 * mB.y;
        a3.z += wA3 * mA.z + wB3 * mB.z; a3.w += wA3 * mA.w + wB3 * mB.w;
    }
    // reduce over the 4 groups within each wave (lanes with same sub)
    #pragma unroll
    for (int m = 16; m <= 32; m <<= 1) {
        a0.x += __shfl_xor(a0.x, m); a0.y += __shfl_xor(a0.y, m);
        a0.z += __shfl_xor(a0.z, m); a0.w += __shfl_xor(a0.w, m);
        a1.x += __shfl_xor(a1.x, m); a1.y += __shfl_xor(a1.y, m);
        a1.z += __shfl_xor(a1.z, m); a1.w += __shfl_xor(a1.w, m);
        a2.x += __shfl_xor(a2.x, m); a2.y += __shfl_xor(a2.y, m);
        a2.z += __shfl_xor(a2.z, m); a2.w += __shfl_xor(a2.w, m);
        a3.x += __shfl_xor(a3.x, m); a3.y += __shfl_xor(a3.y, m);
        a3.z += __shfl_xor(a3.z, m); a3.w += __shfl_xor(a3.w, m);
    }
    if ((tid & 63) < 16) {
        atomicAdd(&zl[0 * 64 + d0 + 0], a0.x); atomicAdd(&zl[0 * 64 + d0 + 1], a0.y);
        atomicAdd(&zl[0 * 64 + d0 + 2], a0.z); atomicAdd(&zl[0 * 64 + d0 + 3], a0.w);
        atomicAdd(&zl[1 * 64 + d0 + 0], a1.x); atomicAdd(&zl[1 * 64 + d0 + 1], a1.y);
        atomicAdd(&zl[1 * 64 + d0 + 2], a1.z); atomicAdd(&zl[1 * 64 + d0 + 3], a1.w);
        atomicAdd(&zl[2 * 64 + d0 + 0], a2.x); atomicAdd(&zl[2 * 64 + d0 + 1], a2.y);
        atomicAdd(&zl[2 * 64 + d0 + 2], a2.z); atomicAdd(&zl[2 * 64 + d0 + 3], a2.w);
        atomicAdd(&zl[3 * 64 + d0 + 0], a3.x); atomicAdd(&zl[3 * 64 + d0 + 1], a3.y);
        atomicAdd(&zl[3 * 64 + d0 + 2], a3.z); atomicAdd(&zl[3 * 64 + d0 + 3], a3.w);
    }
    __syncthreads();
    zpart[(size_t)blockIdx.x * 256 + tid] = zl[tid];
}

// ---- K6b: reduce zpart -> zphi middle dims (deterministic two-stage) ----
__global__ __launch_bounds__(256) void k_zphi_red(const float* __restrict__ zpart,
    float* __restrict__ zphi)
{
    int tid = threadIdx.x;
    float s = 0.f;
    int r0 = blockIdx.x * 32;
    for (int r = r0; r < r0 + 32; ++r)
        s += zpart[(size_t)r * 256 + tid];
    atomicAdd(&zphi[(tid >> 6) * 128 + 32 + (tid & 63)], s);
}

// ---- K6c: zphi z-parts from per-node coefficients: sum csrc/cdst[n][t]*z[n] ----
__global__ __launch_bounds__(256) void k_zphi_nodes(const float* __restrict__ z,
    const float* __restrict__ csrc, const float* __restrict__ cdst, float* __restrict__ zphi)
{
    __shared__ float zl[256];
    int tid = threadIdx.x;
    zl[tid] = 0.f;
    __syncthreads();
    int d = tid & 31, ng = tid >> 5;
    float s0 = 0, s1 = 0, s2 = 0, s3 = 0, t0 = 0, t1 = 0, t2 = 0, t3 = 0;
    for (int n = blockIdx.x * 8 + ng; n < NN; n += gridDim.x * 8) {
        float zv = z[(size_t)n * 32 + d];
        float4 cs = *(const float4*)&csrc[n * 4];
        float4 cd = *(const float4*)&cdst[n * 4];
        s0 += cs.x * zv; s1 += cs.y * zv; s2 += cs.z * zv; s3 += cs.w * zv;
        t0 += cd.x * zv; t1 += cd.y * zv; t2 += cd.z * zv; t3 += cd.w * zv;
    }
    s0 += __shfl_xor(s0, 32); s1 += __shfl_xor(s1, 32);
    s2 += __shfl_xor(s2, 32); s3 += __shfl_xor(s3, 32);
    t0 += __shfl_xor(t0, 32); t1 += __shfl_xor(t1, 32);
    t2 += __shfl_xor(t2, 32); t3 += __shfl_xor(t3, 32);
    if ((tid & 63) < 32) {
        atomicAdd(&zl[0 * 32 + d], s0); atomicAdd(&zl[1 * 32 + d], s1);
        atomicAdd(&zl[2 * 32 + d], s2); atomicAdd(&zl[3 * 32 + d], s3);
        atomicAdd(&zl[128 + 0 * 32 + d], t0); atomicAdd(&zl[128 + 1 * 32 + d], t1);
        atomicAdd(&zl[128 + 2 * 32 + d], t2); atomicAdd(&zl[128 + 3 * 32 + d], t3);
    }
    __syncthreads();
    if (tid < 128) atomicAdd(&zphi[(tid >> 5) * 128 + (tid & 31)], zl[tid]);
    else atomicAdd(&zphi[((tid - 128) >> 5) * 128 + 96 + (tid & 31)], zl[tid]);
}

// ---- K7: beta = softmax(lrelu(zphi @ w_sem)) ----
__global__ __launch_bounds__(128) void k_beta(const float* __restrict__ zphi,
    const float* __restrict__ w_sem, float* __restrict__ beta)
{
    int tid = threadIdx.x;
    float w = w_sem[tid];
    float p0 = zphi[tid] * w, p1 = zphi[128 + tid] * w;
    float p2 = zphi[256 + tid] * w, p3 = zphi[384 + tid] * w;
    #pragma unroll
    for (int m = 32; m >= 1; m >>= 1) {
        p0 += __shfl_xor(p0, m); p1 += __shfl_xor(p1, m);
        p2 += __shfl_xor(p2, m); p3 += __shfl_xor(p3, m);
    }
    __shared__ float s[2][4];
    if ((tid & 63) == 0) {
        int w_ = tid >> 6;
        s[w_][0] = p0; s[w_][1] = p1; s[w_][2] = p2; s[w_][3] = p3;
    }
    __syncthreads();
    if (tid == 0) {
        float d0 = lrelu(s[0][0] + s[1][0]);
        float d1 = lrelu(s[0][1] + s[1][1]);
        float d2 = lrelu(s[0][2] + s[1][2]);
        float d3 = lrelu(s[0][3] + s[1][3]);
        float mx = fmaxf(fmaxf(d0, d1), fmaxf(d2, d3));
        float e0 = expf(d0 - mx), e1 = expf(d1 - mx), e2 = expf(d2 - mx), e3 = expf(d3 - mx);
        float inv = 1.f / (e0 + e1 + e2 + e3);
        beta[0] = e0 * inv; beta[1] = e1 * inv; beta[2] = e2 * inv; beta[3] = e3 * inv;
    }
}

// ---- K8: w[e] = alpha[e] * beta[ety[e]] ----
__global__ void k_walpha(const float* __restrict__ alpha, const int* __restrict__ ety,
                         const float* __restrict__ beta, float* __restrict__ w)
{
    int e = blockIdx.x * 256 + threadIdx.x;
    if (e >= NE) return;
    w[e] = alpha[e] * beta[ety[e]];
}

// ---- K9: CSR scatter — one 32-lane group per node, no atomics, 2-way unroll ----
__global__ __launch_bounds__(256) void k_scatter(const int* __restrict__ offs,
    const int* __restrict__ eidx, const int* __restrict__ src,
    const float* __restrict__ w, const float* __restrict__ z,
    const float* __restrict__ ew, float* __restrict__ hbeta)
{
    int tid = threadIdx.x;
    int lane = tid & 31;
    int grp = tid >> 5;
    int n = blockIdx.x * 8 + grp;
    if (n >= NN) return;
    int d0 = lane * 4;
    int beg = offs[n], end = offs[n + 1];
    float4 acc = make_float4(0, 0, 0, 0);
    float sumw = 0.f;
    int i = beg;
    for (; i + 2 <= end; i += 2) {
        int ea = eidx[i], eb = eidx[i + 1];
        float wa = w[ea], wb = w[eb];
        int sa = src[ea], sb = src[eb];
        sumw += wa + wb;
        if (lane < 24) {
            const float* pa = (lane < 8) ? &z[(size_t)sa * 32 + d0]
                                         : &ew[(size_t)ea * 64 + (d0 - 32)];
            const float* pb = (lane < 8) ? &z[(size_t)sb * 32 + d0]
                                         : &ew[(size_t)eb * 64 + (d0 - 32)];
            float4 ma = *(const float4*)pa;
            float4 mb = *(const float4*)pb;
            acc.x += wa * ma.x + wb * mb.x; acc.y += wa * ma.y + wb * mb.y;
            acc.z += wa * ma.z + wb * mb.z; acc.w += wa * ma.w + wb * mb.w;
        }
    }
    if (i < end) {
        int ea = eidx[i];
        float wa = w[ea];
        int sa = src[ea];
        sumw += wa;
        if (lane < 24) {
            const float* pa = (lane < 8) ? &z[(size_t)sa * 32 + d0]
                                         : &ew[(size_t)ea * 64 + (d0 - 32)];
            float4 ma = *(const float4*)pa;
            acc.x += wa * ma.x; acc.y += wa * ma.y; acc.z += wa * ma.z; acc.w += wa * ma.w;
        }
    }
    if (lane >= 24) {
        float4 zd = *(const float4*)&z[(size_t)n * 32 + (d0 - 96)];
        acc.x = sumw * zd.x; acc.y = sumw * zd.y; acc.z = sumw * zd.z; acc.w = sumw * zd.w;
    }
    *(float4*)&hbeta[(size_t)n * 128 + d0] = acc;
}

// ---- K10: Z = hbeta @ W_fc2 ----
__global__ __launch_bounds__(256) void k_fc(const float* __restrict__ hb,
    const float* __restrict__ W, float* __restrict__ Z)
{
    __shared__ float hl[32 * 132];
    __shared__ float Wl[128 * 64];
    int tid = threadIdx.x;
    int nb = blockIdx.x * 32;
    for (int i = tid; i < 1024; i += 256) {
        int row = i >> 5, kc = (i & 31) * 4;
        float4 v = make_float4(0.f, 0.f, 0.f, 0.f);
        if (nb + row < NN) v = *(const float4*)&hb[(size_t)(nb + row) * 128 + kc];
        *(float4*)&hl[row * 132 + kc] = v;
    }
    for (int half = 0; half < 2; ++half) {
        __syncthreads();
        for (int i = tid; i < 2048; i += 256) {
            int k = i >> 4, c = (i & 15) * 4;
            *(float4*)&Wl[k * 64 + c] = *(const float4*)&W[(size_t)k * 128 + half * 64 + c];
        }
        __syncthreads();
        int node = tid >> 3;
        int c0 = (tid & 7) * 8;
        float acc[8] = {0, 0, 0, 0, 0, 0, 0, 0};
        #pragma unroll 4
        for (int k = 0; k < 128; ++k) {
            float a = hl[node * 132 + k];
            const float* wr = &Wl[k * 64 + c0];
            #pragma unroll
            for (int j = 0; j < 8; ++j) acc[j] += a * wr[j];
        }
        int n = nb + node;
        if (n < NN) {
            float4 o1, o2;
            o1.x = acc[0]; o1.y = acc[1]; o1.z = acc[2]; o1.w = acc[3];
            o2.x = acc[4]; o2.y = acc[5]; o2.z = acc[6]; o2.w = acc[7];
            *(float4*)&Z[(size_t)n * 128 + half * 64 + c0] = o1;
            *(float4*)&Z[(size_t)n * 128 + half * 64 + c0 + 4] = o2;
        }
    }
}

extern "C" void kernel_launch(void* const* d_in, const int* in_sizes, int n_in,
                              void* d_out, int out_size, void* d_ws, size_t ws_size,
                              hipStream_t stream)
{
    const float* nf     = (const float*)d_in[0];
    const float* ef     = (const float*)d_in[1];
    const int*   src    = (const int*)d_in[2];
    const int*   dst    = (const int*)d_in[3];
    const int*   ety    = (const int*)d_in[4];
    const float* W_n    = (const float*)d_in[5];
    const float* W_e    = (const float*)d_in[6];
    const float* w_eattn= (const float*)d_in[7];
    const float* w_attn = (const float*)d_in[8];
    const float* w_sem  = (const float*)d_in[9];
    const float* W_fc2  = (const float*)d_in[10];

    float* out = (float*)d_out;
    float* Z   = out;
    float* ew  = out + (size_t)NN * OUTD;

    float* ws    = (float*)d_ws;
    float* z     = ws + OFF_Z;
    float* a_src = ws + OFF_ASRC;
    float* b_src = ws + OFF_BSRC;
    float* b_dst = ws + OFF_BDST;
    float* c1    = ws + OFF_C1;
    float* c2    = ws + OFF_C2;
    float* s1x   = ws + OFF_S1X;
    float* gamma = ws + OFF_GAMMA;
    float* s2x   = ws + OFF_S2X;
    float* alpha = ws + OFF_S1X;     // alias: s1x dead after k_g2ex
    float* wgt   = ws + OFF_GAMMA;   // alias: gamma dead after k_zphi_stream
    float* zpart = ws + OFF_C1;      // alias: c1/c2 dead after k_g2ex
    float* den1  = ws + OFF_DEN1;
    float* den2  = ws + OFF_DEN2;
    float* zphi  = ws + OFF_ZPHI;
    float* beta  = ws + OFF_BETA;
    float* csrc  = ws + OFF_CSRC;
    float* cdst  = ws + OFF_CDST;
    int* deg     = (int*)(ws + OFF_DEG);
    int* offs    = (int*)(ws + OFF_OFFS);
    int* cursor  = (int*)(ws + OFF_CURSOR);
    int* eidx    = (int*)(ws + OFF_EIDX);
    float* hbeta = ws + OFF_HBETA;

    // zero: den1, den2, zphi, beta, csrc, cdst, deg (contiguous, ~1.1 MB)
    hipMemsetAsync(ws + OFF_DEN1, 0, (size_t)(OFF_OFFS - OFF_DEN1) * 4, stream);

    k_node<<<NN / 8, 256, 0, stream>>>(nf, W_n, w_eattn, w_attn, z, a_src, b_src, b_dst);
    k_edge<<<NE / 64, 256, 0, stream>>>(ef, W_e, w_eattn, w_attn, ew, c1, c2);
    int gE = (NE + 255) / 256;
    k_s1ex<<<gE, 256, 0, stream>>>(c1, a_src, src, dst, s1x, den1, deg);
    k_scan<<<1, 1024, 0, stream>>>(deg, offs, cursor);
    k_g2ex<<<gE, 256, 0, stream>>>(src, dst, s1x, den1, c2, b_src, b_dst, gamma, s2x, den2, cursor, eidx);
    k_zphi_stream<<<ZGRID, 256, 0, stream>>>(src, dst, ety, s2x, den2, gamma, ew, alpha, csrc, cdst, zpart);
    k_zphi_red<<<ZGRID / 32, 256, 0, stream>>>(zpart, zphi);
    k_zphi_nodes<<<128, 256, 0, stream>>>(z, csrc, cdst, zphi);
    k_beta<<<1, 128, 0, stream>>>(zphi, w_sem, beta);
    k_walpha<<<gE, 256, 0, stream>>>(alpha, ety, beta, wgt);
    k_scatter<<<(NN + 7) / 8, 256, 0, stream>>>(offs, eidx, src, wgt, z, ew, hbeta);
    k_fc<<<(NN + 31) / 32, 256, 0, stream>>>(hbeta, W_fc2, Z);
}